// Round 5
// baseline (781.448 us; speedup 1.0000x reference)
//
#include <hip/hip_runtime.h>

typedef _Float16 half_t;
typedef half_t half4 __attribute__((ext_vector_type(4)));
typedef half_t half8 __attribute__((ext_vector_type(8)));
typedef float  f32x4 __attribute__((ext_vector_type(4)));
typedef float  f32x2 __attribute__((ext_vector_type(2)));

constexpr int B_  = 8;
constexpr int S_  = 15;
constexpr int K_  = 17;
constexpr int P_  = 31;
constexpr int SS_ = 225;
constexpr int PP_ = 961;
constexpr int KK_ = 289;

constexpr int NROW_C = B_ * PP_;          // 7688
constexpr int NROW_T = B_ * SS_;          // 1800
constexpr int NROW   = NROW_C + NROW_T;   // 9488

// wf arena: only w0T now
constexpr int W0T  = 0;                   // [512][256]
constexpr int WTOT = 131072;
constexpr int NF16 = 128*256 + 64*128;    // w1h | w2h

// workspace float offsets
constexpr size_t OFF_WF   = 0;
constexpr size_t OFF_IN   = WTOT;
constexpr size_t OFF_OUT0 = OFF_IN   + (size_t)NROW * 256;
constexpr size_t OFF_ROWS = OFF_OUT0 + (size_t)NROW * 512;
constexpr size_t OFF_M0   = OFF_ROWS + (size_t)B_ * 31 * 17 * 256;
constexpr size_t OFF_TM0  = OFF_M0   + (size_t)B_ * KK_ * 256;
constexpr size_t OFF_W1H  = OFF_TM0  + (size_t)B_ * 256;

// chain LDS byte offsets
constexpr int X0B  = 0;       // f16 x0 [64 pos][512B] swz          (32768)
constexpr int X2B  = 0;       // f32 x2T [64 pos][256B] swz (alias) (16384)
constexpr int Y3B  = 16384;   // f32 y3T [64 pos][160B]             (10240)
constexpr int Y4B  = 26624;   // f32 y4T [64 pos][64B]              (4096)
constexpr int X1B  = 32768;   // f16 x1 [64 pos][256B] swz          (16384)
constexpr int SMB  = 49152;   // 240 f logits
constexpr int REDB = 50112;   // 16 f
constexpr int ROWB = 50176;   // 225 u16 row table (pad 464)
constexpr int W4B  = 50640;   // w4 [16][40f]                       (2560)
constexpr int W5B  = 53200;   // w5 [8][20f]                        (640)
constexpr int W6B  = 53840;   // w6 [8]                             (32)
constexpr int LDSB = 53872;

// ---------------------------------------------------------------------------
__global__ __launch_bounds__(256) void prep_kernel(
    const float* __restrict__ templ, const float* __restrict__ cand,
    const float* __restrict__ w0, const float* __restrict__ w1,
    const float* __restrict__ w2,
    float* __restrict__ inarr, float* __restrict__ wf,
    half_t* __restrict__ w1h, half_t* __restrict__ w2h)
{
  const int NA = NROW_C * 256;
  const int NB = NROW_T * 256;
  const int total = NA + NB + WTOT + NF16;
  for (int idx = blockIdx.x * blockDim.x + threadIdx.x; idx < total;
       idx += gridDim.x * blockDim.x) {
    if (idx < NA) {
      int c = idx & 255; int r = idx >> 8;
      int q = r % P_; int p = (r / P_) % P_; int b = r / PP_;
      inarr[idx] = cand[((b * 256 + c) * P_ + p) * P_ + q];
    } else if (idx < NA + NB) {
      int t = idx - NA;
      int c = t & 255; int r = t >> 8;
      int j = r % S_; int i = (r / S_) % S_; int b = r / SS_;
      inarr[idx] = templ[((b * 256 + c) * S_ + i) * S_ + j];
    } else if (idx < NA + NB + WTOT) {
      int t = idx - NA - NB;
      int o = t & 255; int c = t >> 8;
      wf[t] = w0[o * 512 + c];
    } else {
      int t = idx - NA - NB - WTOT;
      if (t < 128 * 256) w1h[t] = (half_t)w1[t];
      else               w2h[t - 128 * 256] = (half_t)w2[t - 128 * 256];
    }
  }
}

// ---------------------------------------------------------------------------
__global__ __launch_bounds__(256) void l0gemm_kernel(
    const float* __restrict__ in, const float* __restrict__ w0T,
    float* __restrict__ out0)
{
  __shared__ float X[256 * 17];
  const int tid = threadIdx.x;
  const int row0 = blockIdx.x * 16;
#pragma unroll
  for (int r = 0; r < 16; ++r)
    X[tid * 17 + r] = in[(size_t)(row0 + r) * 256 + tid];
  __syncthreads();
  float accA[16], accB[16];
#pragma unroll
  for (int r = 0; r < 16; ++r) { accA[r] = 0.f; accB[r] = 0.f; }
  for (int c = 0; c < 256; ++c) {
    float wA = w0T[c * 256 + tid];
    float wB = w0T[(256 + c) * 256 + tid];
#pragma unroll
    for (int r = 0; r < 16; ++r) {
      float x = X[c * 17 + r];
      accB[r] = fmaf(wB, x, accB[r]);
      accA[r] = fmaf(wA, x, accA[r]);
    }
  }
#pragma unroll
  for (int r = 0; r < 16; ++r) {
    out0[(size_t)(row0 + r) * 512 + tid]       = accB[r];
    out0[(size_t)(row0 + r) * 512 + 256 + tid] = accA[r];
  }
}

// ---------------------------------------------------------------------------
__global__ __launch_bounds__(256) void rowsum_kernel(
    const float* __restrict__ out0, float* __restrict__ rows)
{
  const int bid = blockIdx.x;
  const int o = threadIdx.x;
  const int v = bid % 17; const int p = (bid / 17) % 31; const int b = bid / (17 * 31);
  float s = 0.f;
  for (int j = 0; j < 15; ++j)
    s += out0[(size_t)(b * PP_ + p * P_ + v + j) * 512 + 256 + o];
  rows[(size_t)bid * 256 + o] = s;
}

__global__ __launch_bounds__(256) void colsum_kernel(
    const float* __restrict__ rows, float* __restrict__ m0v)
{
  const int bid = blockIdx.x;
  const int o = threadIdx.x;
  const int v = bid % 17; const int u = (bid / 17) % 17; const int b = bid / KK_;
  float s = 0.f;
  for (int i = 0; i < 15; ++i)
    s += rows[(size_t)((b * 31 + u + i) * 17 + v) * 256 + o];
  m0v[(size_t)bid * 256 + o] = s * (1.0f / 225.0f);
}

__global__ __launch_bounds__(256) void tmean0_kernel(
    const float* __restrict__ out0, float* __restrict__ tm0v)
{
  const int b = blockIdx.x;
  const int o = threadIdx.x;
  float s = 0.f;
  for (int t = 0; t < SS_; ++t)
    s += out0[(size_t)(NROW_C + b * SS_ + t) * 512 + 256 + o];
  tm0v[b * 256 + o] = s * (1.0f / 225.0f);
}

// ---------------------------------------------------------------------------
__global__ __launch_bounds__(512, 6) void chain_kernel(
    const float* __restrict__ out0, const float* __restrict__ m0v,
    const float* __restrict__ tm0v,
    const half_t* __restrict__ w1h, const half_t* __restrict__ w2h,
    const float* __restrict__ w3, const float* __restrict__ w4,
    const float* __restrict__ w5, const float* __restrict__ w6,
    const float* __restrict__ inarr, float* __restrict__ out)
{
  __shared__ __align__(16) char lds[LDSB];
  float*    sm     = (float*)(lds + SMB);
  float*    red    = (float*)(lds + REDB);
  uint16_t* rowoff = (uint16_t*)(lds + ROWB);

  const int tid  = threadIdx.x;
  const int lane = tid & 63;
  const int wvs  = __builtin_amdgcn_readfirstlane(tid >> 6);
  const int bid  = (blockIdx.x & 7) * 290 + (blockIdx.x >> 3);   // XCD swizzle (2320 = 8*290)
  const bool is_t = (bid >= B_ * KK_);
  int b, u = 0, v = 0;
  const float* mean_vec;
  if (!is_t) {
    b = bid / KK_;
    int r = bid % KK_;
    u = r / K_; v = r % K_;
    mean_vec = m0v + (size_t)bid * 256;
  } else {
    b = bid - B_ * KK_;
    mean_vec = tm0v + (size_t)b * 256;
  }

  // one-time LDS init: row table + small weights (bank-padded)
  if (tid < SS_) {
    int i = tid / 15, j = tid - i * 15;
    rowoff[tid] = is_t ? (uint16_t)(NROW_C + b * SS_ + tid)
                       : (uint16_t)(b * PP_ + (u + i) * P_ + (v + j));
  }
  ((float*)(lds + W4B))[(tid >> 5) * 40 + (tid & 31)] = w4[tid];   // 512 = 16*32
  if (tid < 128) ((float*)(lds + W5B))[(tid >> 4) * 20 + (tid & 15)] = w5[tid];
  if (tid < 8)   ((float*)(lds + W6B))[tid] = w6[tid];

  // hoisted MFMA A-fragments
  half8 af1[8];
  {
    const half_t* base = w1h + (size_t)(16 * wvs + (lane & 15)) * 256 + ((lane >> 4) << 3);
#pragma unroll
    for (int kb = 0; kb < 8; ++kb) af1[kb] = *(const half8*)(base + kb * 32);
  }
  const int g2 = wvs & 3, h2 = wvs >> 2;
  half8 af2[4];
  {
    const half_t* base = w2h + (size_t)(16 * g2 + (lane & 15)) * 128 + ((lane >> 4) << 3);
#pragma unroll
    for (int kb = 0; kb < 4; ++kb) af2[kb] = *(const half8*)(base + kb * 32);
  }
  const f32x4 mv4 = *(const f32x4*)(mean_vec + 4 * lane);
  __syncthreads();

  for (int s0 = 0; s0 < SS_; s0 += 64) {
    const int cnt = min(64, SS_ - s0);
    // ---- stage x0 = f16(leaky(mean + conv1_window)), [pos][256ch] swz
    for (int t = wvs; t < 64; t += 8) {
      int s = s0 + t; if (s > SS_ - 1) s = SS_ - 1;
      int row = rowoff[s];
      f32x4 x = *(const f32x4*)(out0 + (size_t)row * 512 + 4 * lane);
      half4 h;
#pragma unroll
      for (int r = 0; r < 4; ++r) {
        float a = x[r] + mv4[r];
        a = fmaxf(a, 0.01f * a);
        h[r] = (half_t)a;
      }
      const int off = (t * 512 + lane * 8) ^ ((t & 7) << 4);
      *(half4*)(lds + X0B + off) = h;
    }
    __syncthreads();

    // ---- layer 1: 256 -> 128 MFMA (wave owns 16 out-ch, all 64 pos)
    f32x4 acc[4];
#pragma unroll
    for (int nt = 0; nt < 4; ++nt) acc[nt] = (f32x4){0.f, 0.f, 0.f, 0.f};
#pragma unroll
    for (int kb = 0; kb < 8; ++kb) {
      const int kbyte = kb * 64 + ((lane >> 4) << 4);
#pragma unroll
      for (int nt = 0; nt < 4; ++nt) {
        const int pos = nt * 16 + (lane & 15);
        const int off = (pos * 512 + kbyte) ^ ((pos & 7) << 4);
        half8 bfr = *(const half8*)(lds + X0B + off);
        acc[nt] = __builtin_amdgcn_mfma_f32_16x16x32_f16(af1[kb], bfr, acc[nt], 0, 0, 0);
      }
    }
#pragma unroll
    for (int nt = 0; nt < 4; ++nt) {
      const int pos = nt * 16 + (lane & 15);
      half4 h;
#pragma unroll
      for (int r = 0; r < 4; ++r) {
        float a = acc[nt][r];
        a = fmaxf(a, 0.01f * a);
        h[r] = (half_t)a;
      }
      const int ch0 = 16 * wvs + ((lane >> 4) << 2);
      const int off = (pos * 256 + ch0 * 2) ^ ((pos & 7) << 4);
      *(half4*)(lds + X1B + off) = h;
    }
    __syncthreads();

    // ---- layer 2: 128 -> 64 MFMA; epilogue -> x2T [pos][64ch] f32 swz
    f32x4 acc2[2];
#pragma unroll
    for (int nt = 0; nt < 2; ++nt) acc2[nt] = (f32x4){0.f, 0.f, 0.f, 0.f};
#pragma unroll
    for (int kb = 0; kb < 4; ++kb) {
      const int kbyte = kb * 64 + ((lane >> 4) << 4);
#pragma unroll
      for (int nt = 0; nt < 2; ++nt) {
        const int pos = h2 * 32 + nt * 16 + (lane & 15);
        const int off = (pos * 256 + kbyte) ^ ((pos & 7) << 4);
        half8 bfr = *(const half8*)(lds + X1B + off);
        acc2[nt] = __builtin_amdgcn_mfma_f32_16x16x32_f16(af2[kb], bfr, acc2[nt], 0, 0, 0);
      }
    }
#pragma unroll
    for (int nt = 0; nt < 2; ++nt) {
      const int pos = h2 * 32 + nt * 16 + (lane & 15);
      const int ch0 = 16 * g2 + ((lane >> 4) << 2);
      f32x4 o4;
#pragma unroll
      for (int r = 0; r < 4; ++r) {
        float a = acc2[nt][r];
        o4[r] = fmaxf(a, 0.01f * a);
      }
      const int off = (pos * 256 + ch0 * 4) ^ ((pos & 7) << 4);
      *(f32x4*)(lds + X2B + off) = o4;
    }
    __syncthreads();

    // ---- layer 3: 64 -> 32, channel-sliced (lane = pos), b128 x-reads
    {
      float a3[4] = {0.f, 0.f, 0.f, 0.f};
      const float* w3r = w3 + (4 * wvs) * 64;   // rows 4wvs..4wvs+3, row-major
#pragma unroll
      for (int c0 = 0; c0 < 64; c0 += 4) {
        const int off = (lane * 256 + c0 * 4) ^ ((lane & 7) << 4);
        f32x4 x = *(const f32x4*)(lds + X2B + off);
#pragma unroll
        for (int k = 0; k < 4; ++k)
#pragma unroll
          for (int r = 0; r < 4; ++r)
            a3[k] = fmaf(w3r[k * 64 + c0 + r], x[r], a3[k]);
      }
      f32x4 o4;
#pragma unroll
      for (int k = 0; k < 4; ++k) o4[k] = fmaxf(a3[k], 0.01f * a3[k]);
      *(f32x4*)(lds + Y3B + lane * 160 + wvs * 16) = o4;   // y3T [pos][32ch]
    }
    __syncthreads();

    // ---- layers 4-6 position-sliced per wave (pos 8*wvs .. +7), barrier-free
    {
      const int p = lane >> 3, g = lane & 7;
      const int pos = 8 * wvs + p;
      float a4_0 = 0.f, a4_1 = 0.f;
#pragma unroll
      for (int c0 = 0; c0 < 32; c0 += 4) {
        f32x4 x  = *(const f32x4*)(lds + Y3B + pos * 160 + c0 * 4);
        f32x4 wA = *(const f32x4*)(lds + W4B + (2 * g) * 160 + c0 * 4);
        f32x4 wB = *(const f32x4*)(lds + W4B + (2 * g + 1) * 160 + c0 * 4);
#pragma unroll
        for (int r = 0; r < 4; ++r) {
          a4_0 = fmaf(wA[r], x[r], a4_0);
          a4_1 = fmaf(wB[r], x[r], a4_1);
        }
      }
      f32x2 y4v;
      y4v[0] = fmaxf(a4_0, 0.01f * a4_0);
      y4v[1] = fmaxf(a4_1, 0.01f * a4_1);
      *(f32x2*)(lds + Y4B + pos * 64 + g * 8) = y4v;   // y4T [pos][16ch]
      float a5 = 0.f;
#pragma unroll
      for (int c0 = 0; c0 < 16; c0 += 4) {
        f32x4 x = *(const f32x4*)(lds + Y4B + pos * 64 + c0 * 4);
        f32x4 w = *(const f32x4*)(lds + W5B + g * 80 + c0 * 4);
#pragma unroll
        for (int r = 0; r < 4; ++r) a5 = fmaf(w[r], x[r], a5);
      }
      a5 = fmaxf(a5, 0.01f * a5);
      float t6 = ((float*)(lds + W6B))[g] * a5;
      t6 += __shfl_xor(t6, 1);
      t6 += __shfl_xor(t6, 2);
      t6 += __shfl_xor(t6, 4);
      const int spos = s0 + 8 * wvs + p;
      if (g == 0 && (8 * wvs + p) < cnt) sm[spos] = t6;
    }
    __syncthreads();
  }

  // ---- softmax over 225 logits
  float vv = (tid < SS_) ? sm[tid] : -1e30f;
  float m = vv;
#pragma unroll
  for (int off = 32; off >= 1; off >>= 1) m = fmaxf(m, __shfl_xor(m, off));
  if (lane == 0) red[wvs] = m;
  __syncthreads();
  m = red[0];
#pragma unroll
  for (int w = 1; w < 8; ++w) m = fmaxf(m, red[w]);
  float e = (tid < SS_) ? __expf(vv - m) : 0.f;
  float ss = e;
#pragma unroll
  for (int off = 32; off >= 1; off >>= 1) ss += __shfl_xor(ss, off);
  __syncthreads();
  if (lane == 0) red[wvs] = ss;
  __syncthreads();
  float Stot = red[0];
#pragma unroll
  for (int w = 1; w < 8; ++w) Stot += red[w];
  if (tid < SS_) sm[tid] = e / Stot;
  __syncthreads();

  // ---- weighted channel sum over raw features
  const int c_st = tid & 255;
  const int h_st = tid >> 8;
  float acc3 = 0.f;
  for (int s = h_st; s < SS_; s += 2)
    acc3 = fmaf(sm[s], inarr[(size_t)rowoff[s] * 256 + c_st], acc3);
  __syncthreads();
  float* tmp = (float*)(lds + X0B);
  tmp[tid] = acc3;
  __syncthreads();
  if (tid < 256) {
    float tot = tmp[tid] + tmp[256 + tid];
    if (!is_t) out[2048 + ((size_t)(b * 256 + tid) * 17 + u) * 17 + v] = tot;
    else       out[b * 256 + tid] = tot;
  }
}

// ---------------------------------------------------------------------------
extern "C" void kernel_launch(void* const* d_in, const int* in_sizes, int n_in,
                              void* d_out, int out_size, void* d_ws, size_t ws_size,
                              hipStream_t stream)
{
  const float* templ = (const float*)d_in[0];
  const float* cand  = (const float*)d_in[1];
  const float* w0 = (const float*)d_in[2];
  const float* w1 = (const float*)d_in[3];
  const float* w2 = (const float*)d_in[4];
  const float* w3 = (const float*)d_in[5];
  const float* w4 = (const float*)d_in[6];
  const float* w5 = (const float*)d_in[7];
  const float* w6 = (const float*)d_in[8];

  float* ws    = (float*)d_ws;
  float* wf    = ws + OFF_WF;
  float* inarr = ws + OFF_IN;
  float* out0  = ws + OFF_OUT0;
  float* rows  = ws + OFF_ROWS;
  float* m0v   = ws + OFF_M0;
  float* tm0v  = ws + OFF_TM0;
  half_t* w1h  = (half_t*)(ws + OFF_W1H);
  half_t* w2h  = w1h + 128 * 256;
  float* outf  = (float*)d_out;

  prep_kernel<<<2048, 256, 0, stream>>>(templ, cand, w0, w1, w2, inarr, wf, w1h, w2h);
  l0gemm_kernel<<<NROW / 16, 256, 0, stream>>>(inarr, wf + W0T, out0);
  rowsum_kernel<<<B_ * 31 * 17, 256, 0, stream>>>(out0, rows);
  colsum_kernel<<<B_ * KK_, 256, 0, stream>>>(rows, m0v);
  tmean0_kernel<<<B_, 256, 0, stream>>>(out0, tm0v);
  chain_kernel<<<B_ * KK_ + B_, 512, 0, stream>>>(out0, m0v, tm0v, w1h, w2h,
                                                  w3, w4, w5, w6, inarr, outf);
}

// Round 6
// 583.827 us; speedup vs baseline: 1.3385x; 1.3385x over previous
//
#include <hip/hip_runtime.h>

typedef _Float16 half_t;
typedef half_t half4 __attribute__((ext_vector_type(4)));
typedef half_t half8 __attribute__((ext_vector_type(8)));
typedef float  f32x4 __attribute__((ext_vector_type(4)));
typedef float  f32x2 __attribute__((ext_vector_type(2)));

constexpr int B_  = 8;
constexpr int S_  = 15;
constexpr int K_  = 17;
constexpr int P_  = 31;
constexpr int SS_ = 225;
constexpr int PP_ = 961;
constexpr int KK_ = 289;

constexpr int NROW_C = B_ * PP_;          // 7688
constexpr int NROW_T = B_ * SS_;          // 1800
constexpr int NROW   = NROW_C + NROW_T;   // 9488

// wf arena: only w0T now
constexpr int W0T  = 0;                   // [512][256]
constexpr int WTOT = 131072;
constexpr int NF16 = 128*256 + 64*128;    // w1h | w2h

// workspace float offsets
constexpr size_t OFF_WF   = 0;
constexpr size_t OFF_IN   = WTOT;
constexpr size_t OFF_OUT0 = OFF_IN   + (size_t)NROW * 256;
constexpr size_t OFF_ROWS = OFF_OUT0 + (size_t)NROW * 512;
constexpr size_t OFF_M0   = OFF_ROWS + (size_t)B_ * 31 * 17 * 256;
constexpr size_t OFF_TM0  = OFF_M0   + (size_t)B_ * KK_ * 256;
constexpr size_t OFF_W1H  = OFF_TM0  + (size_t)B_ * 256;

// chain LDS byte offsets
constexpr int X0B  = 0;       // f16 x0 [64 pos][512B] swz          (32768)
constexpr int X2B  = 0;       // f32 x2T [64 pos][256B] swz (alias) (16384)
constexpr int Y3B  = 16384;   // f32 y3T [64 pos][160B]             (10240)
constexpr int Y4B  = 26624;   // f32 y4T [64 pos][64B]              (4096)
constexpr int X1B  = 32768;   // f16 x1 [64 pos][256B] swz          (16384)
constexpr int SMB  = 49152;   // 240 f logits
constexpr int REDB = 50112;   // 16 f
constexpr int ROWB = 50176;   // 225 u16 row table (pad 464)
constexpr int W4B  = 50640;   // w4 [16][40f]                       (2560)
constexpr int W5B  = 53200;   // w5 [8][20f]                        (640)
constexpr int W6B  = 53840;   // w6 [8]                             (32)
constexpr int LDSB = 53872;

// ---------------------------------------------------------------------------
__global__ __launch_bounds__(256) void prep_kernel(
    const float* __restrict__ templ, const float* __restrict__ cand,
    const float* __restrict__ w0, const float* __restrict__ w1,
    const float* __restrict__ w2,
    float* __restrict__ inarr, float* __restrict__ wf,
    half_t* __restrict__ w1h, half_t* __restrict__ w2h)
{
  const int NA = NROW_C * 256;
  const int NB = NROW_T * 256;
  const int total = NA + NB + WTOT + NF16;
  for (int idx = blockIdx.x * blockDim.x + threadIdx.x; idx < total;
       idx += gridDim.x * blockDim.x) {
    if (idx < NA) {
      int c = idx & 255; int r = idx >> 8;
      int q = r % P_; int p = (r / P_) % P_; int b = r / PP_;
      inarr[idx] = cand[((b * 256 + c) * P_ + p) * P_ + q];
    } else if (idx < NA + NB) {
      int t = idx - NA;
      int c = t & 255; int r = t >> 8;
      int j = r % S_; int i = (r / S_) % S_; int b = r / SS_;
      inarr[idx] = templ[((b * 256 + c) * S_ + i) * S_ + j];
    } else if (idx < NA + NB + WTOT) {
      int t = idx - NA - NB;
      int o = t & 255; int c = t >> 8;
      wf[t] = w0[o * 512 + c];
    } else {
      int t = idx - NA - NB - WTOT;
      if (t < 128 * 256) w1h[t] = (half_t)w1[t];
      else               w2h[t - 128 * 256] = (half_t)w2[t - 128 * 256];
    }
  }
}

// ---------------------------------------------------------------------------
__global__ __launch_bounds__(256) void l0gemm_kernel(
    const float* __restrict__ in, const float* __restrict__ w0T,
    float* __restrict__ out0)
{
  __shared__ float X[256 * 17];
  const int tid = threadIdx.x;
  const int row0 = blockIdx.x * 16;
#pragma unroll
  for (int r = 0; r < 16; ++r)
    X[tid * 17 + r] = in[(size_t)(row0 + r) * 256 + tid];
  __syncthreads();
  float accA[16], accB[16];
#pragma unroll
  for (int r = 0; r < 16; ++r) { accA[r] = 0.f; accB[r] = 0.f; }
  for (int c = 0; c < 256; ++c) {
    float wA = w0T[c * 256 + tid];
    float wB = w0T[(256 + c) * 256 + tid];
#pragma unroll
    for (int r = 0; r < 16; ++r) {
      float x = X[c * 17 + r];
      accB[r] = fmaf(wB, x, accB[r]);
      accA[r] = fmaf(wA, x, accA[r]);
    }
  }
#pragma unroll
  for (int r = 0; r < 16; ++r) {
    out0[(size_t)(row0 + r) * 512 + tid]       = accB[r];
    out0[(size_t)(row0 + r) * 512 + 256 + tid] = accA[r];
  }
}

// ---------------------------------------------------------------------------
__global__ __launch_bounds__(256) void rowsum_kernel(
    const float* __restrict__ out0, float* __restrict__ rows)
{
  const int bid = blockIdx.x;
  const int o = threadIdx.x;
  const int v = bid % 17; const int p = (bid / 17) % 31; const int b = bid / (17 * 31);
  float s = 0.f;
  for (int j = 0; j < 15; ++j)
    s += out0[(size_t)(b * PP_ + p * P_ + v + j) * 512 + 256 + o];
  rows[(size_t)bid * 256 + o] = s;
}

__global__ __launch_bounds__(256) void colsum_kernel(
    const float* __restrict__ rows, float* __restrict__ m0v)
{
  const int bid = blockIdx.x;
  const int o = threadIdx.x;
  const int v = bid % 17; const int u = (bid / 17) % 17; const int b = bid / KK_;
  float s = 0.f;
  for (int i = 0; i < 15; ++i)
    s += rows[(size_t)((b * 31 + u + i) * 17 + v) * 256 + o];
  m0v[(size_t)bid * 256 + o] = s * (1.0f / 225.0f);
}

__global__ __launch_bounds__(256) void tmean0_kernel(
    const float* __restrict__ out0, float* __restrict__ tm0v)
{
  const int b = blockIdx.x;
  const int o = threadIdx.x;
  float s = 0.f;
  for (int t = 0; t < SS_; ++t)
    s += out0[(size_t)(NROW_C + b * SS_ + t) * 512 + 256 + o];
  tm0v[b * 256 + o] = s * (1.0f / 225.0f);
}

// ---------------------------------------------------------------------------
__global__ __launch_bounds__(512, 4) void chain_kernel(
    const float* __restrict__ out0, const float* __restrict__ m0v,
    const float* __restrict__ tm0v,
    const half_t* __restrict__ w1h, const half_t* __restrict__ w2h,
    const float* __restrict__ w3, const float* __restrict__ w4,
    const float* __restrict__ w5, const float* __restrict__ w6,
    const float* __restrict__ inarr, float* __restrict__ out)
{
  __shared__ __align__(16) char lds[LDSB];
  float*    sm     = (float*)(lds + SMB);
  float*    red    = (float*)(lds + REDB);
  uint16_t* rowoff = (uint16_t*)(lds + ROWB);

  const int tid  = threadIdx.x;
  const int lane = tid & 63;
  const int wvs  = __builtin_amdgcn_readfirstlane(tid >> 6);
  const int bid  = (blockIdx.x & 7) * 290 + (blockIdx.x >> 3);   // XCD swizzle (2320 = 8*290)
  const bool is_t = (bid >= B_ * KK_);
  int b, u = 0, v = 0;
  const float* mean_vec;
  if (!is_t) {
    b = bid / KK_;
    int r = bid % KK_;
    u = r / K_; v = r % K_;
    mean_vec = m0v + (size_t)bid * 256;
  } else {
    b = bid - B_ * KK_;
    mean_vec = tm0v + (size_t)b * 256;
  }

  // one-time LDS init: row table + small weights (bank-padded)
  if (tid < SS_) {
    int i = tid / 15, j = tid - i * 15;
    rowoff[tid] = is_t ? (uint16_t)(NROW_C + b * SS_ + tid)
                       : (uint16_t)(b * PP_ + (u + i) * P_ + (v + j));
  }
  ((float*)(lds + W4B))[(tid >> 5) * 40 + (tid & 31)] = w4[tid];   // 512 = 16*32
  if (tid < 128) ((float*)(lds + W5B))[(tid >> 4) * 20 + (tid & 15)] = w5[tid];
  if (tid < 8)   ((float*)(lds + W6B))[tid] = w6[tid];

  // hoisted MFMA A-fragments
  half8 af1[8];
  {
    const half_t* base = w1h + (size_t)(16 * wvs + (lane & 15)) * 256 + ((lane >> 4) << 3);
#pragma unroll
    for (int kb = 0; kb < 8; ++kb) af1[kb] = *(const half8*)(base + kb * 32);
  }
  const int g2 = wvs & 3, h2 = wvs >> 2;
  half8 af2[4];
  {
    const half_t* base = w2h + (size_t)(16 * g2 + (lane & 15)) * 128 + ((lane >> 4) << 3);
#pragma unroll
    for (int kb = 0; kb < 4; ++kb) af2[kb] = *(const half8*)(base + kb * 32);
  }
  const f32x4 mv4 = *(const f32x4*)(mean_vec + 4 * lane);
  __syncthreads();

  for (int s0 = 0; s0 < SS_; s0 += 64) {
    const int cnt = min(64, SS_ - s0);
    // ---- stage x0 = f16(leaky(mean + conv1_window)), [pos][256ch] swz
    for (int t = wvs; t < 64; t += 8) {
      int s = s0 + t; if (s > SS_ - 1) s = SS_ - 1;
      int row = rowoff[s];
      f32x4 x = *(const f32x4*)(out0 + (size_t)row * 512 + 4 * lane);
      half4 h;
#pragma unroll
      for (int r = 0; r < 4; ++r) {
        float a = x[r] + mv4[r];
        a = fmaxf(a, 0.01f * a);
        h[r] = (half_t)a;
      }
      const int off = (t * 512 + lane * 8) ^ ((t & 7) << 4);
      *(half4*)(lds + X0B + off) = h;
    }
    __syncthreads();

    // ---- layer 1: 256 -> 128 MFMA (wave owns 16 out-ch, all 64 pos)
    f32x4 acc[4];
#pragma unroll
    for (int nt = 0; nt < 4; ++nt) acc[nt] = (f32x4){0.f, 0.f, 0.f, 0.f};
#pragma unroll
    for (int kb = 0; kb < 8; ++kb) {
      const int kbyte = kb * 64 + ((lane >> 4) << 4);
#pragma unroll
      for (int nt = 0; nt < 4; ++nt) {
        const int pos = nt * 16 + (lane & 15);
        const int off = (pos * 512 + kbyte) ^ ((pos & 7) << 4);
        half8 bfr = *(const half8*)(lds + X0B + off);
        acc[nt] = __builtin_amdgcn_mfma_f32_16x16x32_f16(af1[kb], bfr, acc[nt], 0, 0, 0);
      }
    }
#pragma unroll
    for (int nt = 0; nt < 4; ++nt) {
      const int pos = nt * 16 + (lane & 15);
      half4 h;
#pragma unroll
      for (int r = 0; r < 4; ++r) {
        float a = acc[nt][r];
        a = fmaxf(a, 0.01f * a);
        h[r] = (half_t)a;
      }
      const int ch0 = 16 * wvs + ((lane >> 4) << 2);
      const int off = (pos * 256 + ch0 * 2) ^ ((pos & 7) << 4);
      *(half4*)(lds + X1B + off) = h;
    }
    __syncthreads();

    // ---- layer 2: 128 -> 64 MFMA; epilogue -> x2T [pos][64ch] f32 swz
    f32x4 acc2[2];
#pragma unroll
    for (int nt = 0; nt < 2; ++nt) acc2[nt] = (f32x4){0.f, 0.f, 0.f, 0.f};
#pragma unroll
    for (int kb = 0; kb < 4; ++kb) {
      const int kbyte = kb * 64 + ((lane >> 4) << 4);
#pragma unroll
      for (int nt = 0; nt < 2; ++nt) {
        const int pos = h2 * 32 + nt * 16 + (lane & 15);
        const int off = (pos * 256 + kbyte) ^ ((pos & 7) << 4);
        half8 bfr = *(const half8*)(lds + X1B + off);
        acc2[nt] = __builtin_amdgcn_mfma_f32_16x16x32_f16(af2[kb], bfr, acc2[nt], 0, 0, 0);
      }
    }
#pragma unroll
    for (int nt = 0; nt < 2; ++nt) {
      const int pos = h2 * 32 + nt * 16 + (lane & 15);
      const int ch0 = 16 * g2 + ((lane >> 4) << 2);
      f32x4 o4;
#pragma unroll
      for (int r = 0; r < 4; ++r) {
        float a = acc2[nt][r];
        o4[r] = fmaxf(a, 0.01f * a);
      }
      const int off = (pos * 256 + ch0 * 4) ^ ((pos & 7) << 4);
      *(f32x4*)(lds + X2B + off) = o4;
    }
    __syncthreads();

    // ---- layer 3: 64 -> 32, channel-sliced (lane = pos), b128 x-reads
    {
      float a3[4] = {0.f, 0.f, 0.f, 0.f};
      const float* w3r = w3 + (4 * wvs) * 64;   // rows 4wvs..4wvs+3, row-major
#pragma unroll
      for (int c0 = 0; c0 < 64; c0 += 4) {
        const int off = (lane * 256 + c0 * 4) ^ ((lane & 7) << 4);
        f32x4 x = *(const f32x4*)(lds + X2B + off);
#pragma unroll
        for (int k = 0; k < 4; ++k)
#pragma unroll
          for (int r = 0; r < 4; ++r)
            a3[k] = fmaf(w3r[k * 64 + c0 + r], x[r], a3[k]);
      }
      f32x4 o4;
#pragma unroll
      for (int k = 0; k < 4; ++k) o4[k] = fmaxf(a3[k], 0.01f * a3[k]);
      *(f32x4*)(lds + Y3B + lane * 160 + wvs * 16) = o4;   // y3T [pos][32ch]
    }
    __syncthreads();

    // ---- layers 4-6 position-sliced per wave (pos 8*wvs .. +7), barrier-free
    {
      const int p = lane >> 3, g = lane & 7;
      const int pos = 8 * wvs + p;
      float a4_0 = 0.f, a4_1 = 0.f;
#pragma unroll
      for (int c0 = 0; c0 < 32; c0 += 4) {
        f32x4 x  = *(const f32x4*)(lds + Y3B + pos * 160 + c0 * 4);
        f32x4 wA = *(const f32x4*)(lds + W4B + (2 * g) * 160 + c0 * 4);
        f32x4 wB = *(const f32x4*)(lds + W4B + (2 * g + 1) * 160 + c0 * 4);
#pragma unroll
        for (int r = 0; r < 4; ++r) {
          a4_0 = fmaf(wA[r], x[r], a4_0);
          a4_1 = fmaf(wB[r], x[r], a4_1);
        }
      }
      f32x2 y4v;
      y4v[0] = fmaxf(a4_0, 0.01f * a4_0);
      y4v[1] = fmaxf(a4_1, 0.01f * a4_1);
      *(f32x2*)(lds + Y4B + pos * 64 + g * 8) = y4v;   // y4T [pos][16ch]
      float a5 = 0.f;
#pragma unroll
      for (int c0 = 0; c0 < 16; c0 += 4) {
        f32x4 x = *(const f32x4*)(lds + Y4B + pos * 64 + c0 * 4);
        f32x4 w = *(const f32x4*)(lds + W5B + g * 80 + c0 * 4);
#pragma unroll
        for (int r = 0; r < 4; ++r) a5 = fmaf(w[r], x[r], a5);
      }
      a5 = fmaxf(a5, 0.01f * a5);
      float t6 = ((float*)(lds + W6B))[g] * a5;
      t6 += __shfl_xor(t6, 1);
      t6 += __shfl_xor(t6, 2);
      t6 += __shfl_xor(t6, 4);
      const int spos = s0 + 8 * wvs + p;
      if (g == 0 && (8 * wvs + p) < cnt) sm[spos] = t6;
    }
    __syncthreads();
  }

  // ---- softmax over 225 logits
  float vv = (tid < SS_) ? sm[tid] : -1e30f;
  float m = vv;
#pragma unroll
  for (int off = 32; off >= 1; off >>= 1) m = fmaxf(m, __shfl_xor(m, off));
  if (lane == 0) red[wvs] = m;
  __syncthreads();
  m = red[0];
#pragma unroll
  for (int w = 1; w < 8; ++w) m = fmaxf(m, red[w]);
  float e = (tid < SS_) ? __expf(vv - m) : 0.f;
  float ss = e;
#pragma unroll
  for (int off = 32; off >= 1; off >>= 1) ss += __shfl_xor(ss, off);
  __syncthreads();
  if (lane == 0) red[wvs] = ss;
  __syncthreads();
  float Stot = red[0];
#pragma unroll
  for (int w = 1; w < 8; ++w) Stot += red[w];
  if (tid < SS_) sm[tid] = e / Stot;
  __syncthreads();

  // ---- weighted channel sum over raw features
  const int c_st = tid & 255;
  const int h_st = tid >> 8;
  float acc3 = 0.f;
  for (int s = h_st; s < SS_; s += 2)
    acc3 = fmaf(sm[s], inarr[(size_t)rowoff[s] * 256 + c_st], acc3);
  __syncthreads();
  float* tmp = (float*)(lds + X0B);
  tmp[tid] = acc3;
  __syncthreads();
  if (tid < 256) {
    float tot = tmp[tid] + tmp[256 + tid];
    if (!is_t) out[2048 + ((size_t)(b * 256 + tid) * 17 + u) * 17 + v] = tot;
    else       out[b * 256 + tid] = tot;
  }
}

// ---------------------------------------------------------------------------
extern "C" void kernel_launch(void* const* d_in, const int* in_sizes, int n_in,
                              void* d_out, int out_size, void* d_ws, size_t ws_size,
                              hipStream_t stream)
{
  const float* templ = (const float*)d_in[0];
  const float* cand  = (const float*)d_in[1];
  const float* w0 = (const float*)d_in[2];
  const float* w1 = (const float*)d_in[3];
  const float* w2 = (const float*)d_in[4];
  const float* w3 = (const float*)d_in[5];
  const float* w4 = (const float*)d_in[6];
  const float* w5 = (const float*)d_in[7];
  const float* w6 = (const float*)d_in[8];

  float* ws    = (float*)d_ws;
  float* wf    = ws + OFF_WF;
  float* inarr = ws + OFF_IN;
  float* out0  = ws + OFF_OUT0;
  float* rows  = ws + OFF_ROWS;
  float* m0v   = ws + OFF_M0;
  float* tm0v  = ws + OFF_TM0;
  half_t* w1h  = (half_t*)(ws + OFF_W1H);
  half_t* w2h  = w1h + 128 * 256;
  float* outf  = (float*)d_out;

  prep_kernel<<<2048, 256, 0, stream>>>(templ, cand, w0, w1, w2, inarr, wf, w1h, w2h);
  l0gemm_kernel<<<NROW / 16, 256, 0, stream>>>(inarr, wf + W0T, out0);
  rowsum_kernel<<<B_ * 31 * 17, 256, 0, stream>>>(out0, rows);
  colsum_kernel<<<B_ * KK_, 256, 0, stream>>>(rows, m0v);
  tmean0_kernel<<<B_, 256, 0, stream>>>(out0, tm0v);
  chain_kernel<<<B_ * KK_ + B_, 512, 0, stream>>>(out0, m0v, tm0v, w1h, w2h,
                                                  w3, w4, w5, w6, inarr, outf);
}

// Round 7
// 555.377 us; speedup vs baseline: 1.4071x; 1.0512x over previous
//
#include <hip/hip_runtime.h>

typedef _Float16 half_t;
typedef half_t half4 __attribute__((ext_vector_type(4)));
typedef half_t half8 __attribute__((ext_vector_type(8)));
typedef float  f32x4 __attribute__((ext_vector_type(4)));
typedef float  f32x2 __attribute__((ext_vector_type(2)));

constexpr int B_  = 8;
constexpr int S_  = 15;
constexpr int K_  = 17;
constexpr int P_  = 31;
constexpr int SS_ = 225;
constexpr int PP_ = 961;
constexpr int KK_ = 289;

constexpr int NROW_C = B_ * PP_;          // 7688
constexpr int NROW_T = B_ * SS_;          // 1800
constexpr int NROW   = NROW_C + NROW_T;   // 9488

// wf arena: only w0T now
constexpr int W0T  = 0;                   // [512][256]
constexpr int WTOT = 131072;
constexpr int NF16 = 128*256 + 64*128;    // w1h | w2h

// workspace float offsets
constexpr size_t OFF_WF   = 0;
constexpr size_t OFF_IN   = WTOT;
constexpr size_t OFF_OUT0 = OFF_IN   + (size_t)NROW * 256;
constexpr size_t OFF_ROWS = OFF_OUT0 + (size_t)NROW * 512;
constexpr size_t OFF_M0   = OFF_ROWS + (size_t)B_ * 31 * 17 * 256;
constexpr size_t OFF_TM0  = OFF_M0   + (size_t)B_ * KK_ * 256;
constexpr size_t OFF_W1H  = OFF_TM0  + (size_t)B_ * 256;

// chain LDS byte offsets
constexpr int X0B  = 0;       // f16 x0 [64 pos][512B] swz          (32768)
constexpr int X2B  = 0;       // f32 x2T [64 pos][256B] swz (alias) (16384)
constexpr int Y3B  = 16384;   // f32 y3T [64 pos][160B]             (10240)
constexpr int Y4B  = 26624;   // f32 y4T [64 pos][64B]              (4096)
constexpr int X1B  = 32768;   // f16 x1 [64 pos][256B] swz          (16384)
constexpr int SMB  = 49152;   // 240 f logits
constexpr int REDB = 50112;   // 16 f
constexpr int ROWB = 50176;   // 225 u16 row table (pad 464)
constexpr int W4B  = 50640;   // w4 [16][40f]                       (2560)
constexpr int W5B  = 53200;   // w5 [8][20f]                        (640)
constexpr int W6B  = 53840;   // w6 [8]                             (32)
constexpr int LDSB = 53872;

// ---------------------------------------------------------------------------
__global__ __launch_bounds__(256) void prep_kernel(
    const float* __restrict__ templ, const float* __restrict__ cand,
    const float* __restrict__ w0, const float* __restrict__ w1,
    const float* __restrict__ w2,
    float* __restrict__ inarr, float* __restrict__ wf,
    half_t* __restrict__ w1h, half_t* __restrict__ w2h)
{
  const int NA = NROW_C * 256;
  const int NB = NROW_T * 256;
  const int total = NA + NB + WTOT + NF16;
  for (int idx = blockIdx.x * blockDim.x + threadIdx.x; idx < total;
       idx += gridDim.x * blockDim.x) {
    if (idx < NA) {
      int c = idx & 255; int r = idx >> 8;
      int q = r % P_; int p = (r / P_) % P_; int b = r / PP_;
      inarr[idx] = cand[((b * 256 + c) * P_ + p) * P_ + q];
    } else if (idx < NA + NB) {
      int t = idx - NA;
      int c = t & 255; int r = t >> 8;
      int j = r % S_; int i = (r / S_) % S_; int b = r / SS_;
      inarr[idx] = templ[((b * 256 + c) * S_ + i) * S_ + j];
    } else if (idx < NA + NB + WTOT) {
      int t = idx - NA - NB;
      int o = t & 255; int c = t >> 8;
      wf[t] = w0[o * 512 + c];
    } else {
      int t = idx - NA - NB - WTOT;
      if (t < 128 * 256) w1h[t] = (half_t)w1[t];
      else               w2h[t - 128 * 256] = (half_t)w2[t - 128 * 256];
    }
  }
}

// ---------------------------------------------------------------------------
__global__ __launch_bounds__(256) void l0gemm_kernel(
    const float* __restrict__ in, const float* __restrict__ w0T,
    float* __restrict__ out0)
{
  __shared__ float X[256 * 17];
  const int tid = threadIdx.x;
  const int row0 = blockIdx.x * 16;
#pragma unroll
  for (int r = 0; r < 16; ++r)
    X[tid * 17 + r] = in[(size_t)(row0 + r) * 256 + tid];
  __syncthreads();
  float accA[16], accB[16];
#pragma unroll
  for (int r = 0; r < 16; ++r) { accA[r] = 0.f; accB[r] = 0.f; }
  for (int c = 0; c < 256; ++c) {
    float wA = w0T[c * 256 + tid];
    float wB = w0T[(256 + c) * 256 + tid];
#pragma unroll
    for (int r = 0; r < 16; ++r) {
      float x = X[c * 17 + r];
      accB[r] = fmaf(wB, x, accB[r]);
      accA[r] = fmaf(wA, x, accA[r]);
    }
  }
#pragma unroll
  for (int r = 0; r < 16; ++r) {
    out0[(size_t)(row0 + r) * 512 + tid]       = accB[r];
    out0[(size_t)(row0 + r) * 512 + 256 + tid] = accA[r];
  }
}

// ---------------------------------------------------------------------------
__global__ __launch_bounds__(256) void rowsum_kernel(
    const float* __restrict__ out0, float* __restrict__ rows)
{
  const int bid = blockIdx.x;
  const int o = threadIdx.x;
  const int v = bid % 17; const int p = (bid / 17) % 31; const int b = bid / (17 * 31);
  float s = 0.f;
  for (int j = 0; j < 15; ++j)
    s += out0[(size_t)(b * PP_ + p * P_ + v + j) * 512 + 256 + o];
  rows[(size_t)bid * 256 + o] = s;
}

__global__ __launch_bounds__(256) void colsum_kernel(
    const float* __restrict__ rows, float* __restrict__ m0v)
{
  const int bid = blockIdx.x;
  const int o = threadIdx.x;
  const int v = bid % 17; const int u = (bid / 17) % 17; const int b = bid / KK_;
  float s = 0.f;
  for (int i = 0; i < 15; ++i)
    s += rows[(size_t)((b * 31 + u + i) * 17 + v) * 256 + o];
  m0v[(size_t)bid * 256 + o] = s * (1.0f / 225.0f);
}

__global__ __launch_bounds__(256) void tmean0_kernel(
    const float* __restrict__ out0, float* __restrict__ tm0v)
{
  const int b = blockIdx.x;
  const int o = threadIdx.x;
  float s = 0.f;
  for (int t = 0; t < SS_; ++t)
    s += out0[(size_t)(NROW_C + b * SS_ + t) * 512 + 256 + o];
  tm0v[b * 256 + o] = s * (1.0f / 225.0f);
}

// ---------------------------------------------------------------------------
__global__ __launch_bounds__(512, 2) void chain_kernel(
    const float* __restrict__ out0, const float* __restrict__ m0v,
    const float* __restrict__ tm0v,
    const half_t* __restrict__ w1h, const half_t* __restrict__ w2h,
    const float* __restrict__ w3, const float* __restrict__ w4,
    const float* __restrict__ w5, const float* __restrict__ w6,
    const float* __restrict__ inarr, float* __restrict__ out)
{
  __shared__ __align__(16) char lds[LDSB];
  float*    sm     = (float*)(lds + SMB);
  float*    red    = (float*)(lds + REDB);
  uint16_t* rowoff = (uint16_t*)(lds + ROWB);

  const int tid  = threadIdx.x;
  const int lane = tid & 63;
  const int wvs  = __builtin_amdgcn_readfirstlane(tid >> 6);
  const int bid  = (blockIdx.x & 7) * 290 + (blockIdx.x >> 3);   // XCD swizzle (2320 = 8*290)
  const bool is_t = (bid >= B_ * KK_);
  int b, u = 0, v = 0;
  const float* mean_vec;
  if (!is_t) {
    b = bid / KK_;
    int r = bid % KK_;
    u = r / K_; v = r % K_;
    mean_vec = m0v + (size_t)bid * 256;
  } else {
    b = bid - B_ * KK_;
    mean_vec = tm0v + (size_t)b * 256;
  }

  // one-time LDS init: row table + small weights (bank-padded)
  if (tid < SS_) {
    int i = tid / 15, j = tid - i * 15;
    rowoff[tid] = is_t ? (uint16_t)(NROW_C + b * SS_ + tid)
                       : (uint16_t)(b * PP_ + (u + i) * P_ + (v + j));
  }
  ((float*)(lds + W4B))[(tid >> 5) * 40 + (tid & 31)] = w4[tid];   // 512 = 16*32
  if (tid < 128) ((float*)(lds + W5B))[(tid >> 4) * 20 + (tid & 15)] = w5[tid];
  if (tid < 8)   ((float*)(lds + W6B))[tid] = w6[tid];

  // hoisted MFMA A-fragments
  half8 af1[8];
  {
    const half_t* base = w1h + (size_t)(16 * wvs + (lane & 15)) * 256 + ((lane >> 4) << 3);
#pragma unroll
    for (int kb = 0; kb < 8; ++kb) af1[kb] = *(const half8*)(base + kb * 32);
  }
  const int g2 = wvs & 3, h2 = wvs >> 2;
  half8 af2[4];
  {
    const half_t* base = w2h + (size_t)(16 * g2 + (lane & 15)) * 128 + ((lane >> 4) << 3);
#pragma unroll
    for (int kb = 0; kb < 4; ++kb) af2[kb] = *(const half8*)(base + kb * 32);
  }
  const f32x4 mv4 = *(const f32x4*)(mean_vec + 4 * lane);
  __syncthreads();

  for (int s0 = 0; s0 < SS_; s0 += 64) {
    const int cnt = min(64, SS_ - s0);
    // ---- stage x0 = f16(leaky(mean + conv1_window)), [pos][256ch] swz
    for (int t = wvs; t < 64; t += 8) {
      int s = s0 + t; if (s > SS_ - 1) s = SS_ - 1;
      int row = rowoff[s];
      f32x4 x = *(const f32x4*)(out0 + (size_t)row * 512 + 4 * lane);
      half4 h;
#pragma unroll
      for (int r = 0; r < 4; ++r) {
        float a = x[r] + mv4[r];
        a = fmaxf(a, 0.01f * a);
        h[r] = (half_t)a;
      }
      const int off = (t * 512 + lane * 8) ^ ((t & 7) << 4);
      *(half4*)(lds + X0B + off) = h;
    }
    __syncthreads();

    // ---- layer 1: 256 -> 128 MFMA (wave owns 16 out-ch, all 64 pos)
    f32x4 acc[4];
#pragma unroll
    for (int nt = 0; nt < 4; ++nt) acc[nt] = (f32x4){0.f, 0.f, 0.f, 0.f};
#pragma unroll
    for (int kb = 0; kb < 8; ++kb) {
      const int kbyte = kb * 64 + ((lane >> 4) << 4);
#pragma unroll
      for (int nt = 0; nt < 4; ++nt) {
        const int pos = nt * 16 + (lane & 15);
        const int off = (pos * 512 + kbyte) ^ ((pos & 7) << 4);
        half8 bfr = *(const half8*)(lds + X0B + off);
        acc[nt] = __builtin_amdgcn_mfma_f32_16x16x32_f16(af1[kb], bfr, acc[nt], 0, 0, 0);
      }
    }
#pragma unroll
    for (int nt = 0; nt < 4; ++nt) {
      const int pos = nt * 16 + (lane & 15);
      half4 h;
#pragma unroll
      for (int r = 0; r < 4; ++r) {
        float a = acc[nt][r];
        a = fmaxf(a, 0.01f * a);
        h[r] = (half_t)a;
      }
      const int ch0 = 16 * wvs + ((lane >> 4) << 2);
      const int off = (pos * 256 + ch0 * 2) ^ ((pos & 7) << 4);
      *(half4*)(lds + X1B + off) = h;
    }
    __syncthreads();

    // ---- layer 2: 128 -> 64 MFMA; epilogue -> x2T [pos][64ch] f32 swz
    f32x4 acc2[2];
#pragma unroll
    for (int nt = 0; nt < 2; ++nt) acc2[nt] = (f32x4){0.f, 0.f, 0.f, 0.f};
#pragma unroll
    for (int kb = 0; kb < 4; ++kb) {
      const int kbyte = kb * 64 + ((lane >> 4) << 4);
#pragma unroll
      for (int nt = 0; nt < 2; ++nt) {
        const int pos = h2 * 32 + nt * 16 + (lane & 15);
        const int off = (pos * 256 + kbyte) ^ ((pos & 7) << 4);
        half8 bfr = *(const half8*)(lds + X1B + off);
        acc2[nt] = __builtin_amdgcn_mfma_f32_16x16x32_f16(af2[kb], bfr, acc2[nt], 0, 0, 0);
      }
    }
#pragma unroll
    for (int nt = 0; nt < 2; ++nt) {
      const int pos = h2 * 32 + nt * 16 + (lane & 15);
      const int ch0 = 16 * g2 + ((lane >> 4) << 2);
      f32x4 o4;
#pragma unroll
      for (int r = 0; r < 4; ++r) {
        float a = acc2[nt][r];
        o4[r] = fmaxf(a, 0.01f * a);
      }
      const int off = (pos * 256 + ch0 * 4) ^ ((pos & 7) << 4);
      *(f32x4*)(lds + X2B + off) = o4;
    }
    __syncthreads();

    // ---- layer 3: 64 -> 32, channel-sliced (lane = pos), b128 x-reads
    {
      float a3[4] = {0.f, 0.f, 0.f, 0.f};
      const float* w3r = w3 + (4 * wvs) * 64;   // rows 4wvs..4wvs+3, row-major
#pragma unroll
      for (int c0 = 0; c0 < 64; c0 += 4) {
        const int off = (lane * 256 + c0 * 4) ^ ((lane & 7) << 4);
        f32x4 x = *(const f32x4*)(lds + X2B + off);
#pragma unroll
        for (int k = 0; k < 4; ++k)
#pragma unroll
          for (int r = 0; r < 4; ++r)
            a3[k] = fmaf(w3r[k * 64 + c0 + r], x[r], a3[k]);
      }
      f32x4 o4;
#pragma unroll
      for (int k = 0; k < 4; ++k) o4[k] = fmaxf(a3[k], 0.01f * a3[k]);
      *(f32x4*)(lds + Y3B + lane * 160 + wvs * 16) = o4;   // y3T [pos][32ch]
    }
    __syncthreads();

    // ---- layers 4-6 position-sliced per wave (pos 8*wvs .. +7), barrier-free
    {
      const int p = lane >> 3, g = lane & 7;
      const int pos = 8 * wvs + p;
      float a4_0 = 0.f, a4_1 = 0.f;
#pragma unroll
      for (int c0 = 0; c0 < 32; c0 += 4) {
        f32x4 x  = *(const f32x4*)(lds + Y3B + pos * 160 + c0 * 4);
        f32x4 wA = *(const f32x4*)(lds + W4B + (2 * g) * 160 + c0 * 4);
        f32x4 wB = *(const f32x4*)(lds + W4B + (2 * g + 1) * 160 + c0 * 4);
#pragma unroll
        for (int r = 0; r < 4; ++r) {
          a4_0 = fmaf(wA[r], x[r], a4_0);
          a4_1 = fmaf(wB[r], x[r], a4_1);
        }
      }
      f32x2 y4v;
      y4v[0] = fmaxf(a4_0, 0.01f * a4_0);
      y4v[1] = fmaxf(a4_1, 0.01f * a4_1);
      *(f32x2*)(lds + Y4B + pos * 64 + g * 8) = y4v;   // y4T [pos][16ch]
      float a5 = 0.f;
#pragma unroll
      for (int c0 = 0; c0 < 16; c0 += 4) {
        f32x4 x = *(const f32x4*)(lds + Y4B + pos * 64 + c0 * 4);
        f32x4 w = *(const f32x4*)(lds + W5B + g * 80 + c0 * 4);
#pragma unroll
        for (int r = 0; r < 4; ++r) a5 = fmaf(w[r], x[r], a5);
      }
      a5 = fmaxf(a5, 0.01f * a5);
      float t6 = ((float*)(lds + W6B))[g] * a5;
      t6 += __shfl_xor(t6, 1);
      t6 += __shfl_xor(t6, 2);
      t6 += __shfl_xor(t6, 4);
      const int spos = s0 + 8 * wvs + p;
      if (g == 0 && (8 * wvs + p) < cnt) sm[spos] = t6;
    }
    __syncthreads();
  }

  // ---- softmax over 225 logits
  float vv = (tid < SS_) ? sm[tid] : -1e30f;
  float m = vv;
#pragma unroll
  for (int off = 32; off >= 1; off >>= 1) m = fmaxf(m, __shfl_xor(m, off));
  if (lane == 0) red[wvs] = m;
  __syncthreads();
  m = red[0];
#pragma unroll
  for (int w = 1; w < 8; ++w) m = fmaxf(m, red[w]);
  float e = (tid < SS_) ? __expf(vv - m) : 0.f;
  float ss = e;
#pragma unroll
  for (int off = 32; off >= 1; off >>= 1) ss += __shfl_xor(ss, off);
  __syncthreads();
  if (lane == 0) red[wvs] = ss;
  __syncthreads();
  float Stot = red[0];
#pragma unroll
  for (int w = 1; w < 8; ++w) Stot += red[w];
  if (tid < SS_) sm[tid] = e / Stot;
  __syncthreads();

  // ---- weighted channel sum over raw features
  const int c_st = tid & 255;
  const int h_st = tid >> 8;
  float acc3 = 0.f;
  for (int s = h_st; s < SS_; s += 2)
    acc3 = fmaf(sm[s], inarr[(size_t)rowoff[s] * 256 + c_st], acc3);
  __syncthreads();
  float* tmp = (float*)(lds + X0B);
  tmp[tid] = acc3;
  __syncthreads();
  if (tid < 256) {
    float tot = tmp[tid] + tmp[256 + tid];
    if (!is_t) out[2048 + ((size_t)(b * 256 + tid) * 17 + u) * 17 + v] = tot;
    else       out[b * 256 + tid] = tot;
  }
}

// ---------------------------------------------------------------------------
extern "C" void kernel_launch(void* const* d_in, const int* in_sizes, int n_in,
                              void* d_out, int out_size, void* d_ws, size_t ws_size,
                              hipStream_t stream)
{
  const float* templ = (const float*)d_in[0];
  const float* cand  = (const float*)d_in[1];
  const float* w0 = (const float*)d_in[2];
  const float* w1 = (const float*)d_in[3];
  const float* w2 = (const float*)d_in[4];
  const float* w3 = (const float*)d_in[5];
  const float* w4 = (const float*)d_in[6];
  const float* w5 = (const float*)d_in[7];
  const float* w6 = (const float*)d_in[8];

  float* ws    = (float*)d_ws;
  float* wf    = ws + OFF_WF;
  float* inarr = ws + OFF_IN;
  float* out0  = ws + OFF_OUT0;
  float* rows  = ws + OFF_ROWS;
  float* m0v   = ws + OFF_M0;
  float* tm0v  = ws + OFF_TM0;
  half_t* w1h  = (half_t*)(ws + OFF_W1H);
  half_t* w2h  = w1h + 128 * 256;
  float* outf  = (float*)d_out;

  prep_kernel<<<2048, 256, 0, stream>>>(templ, cand, w0, w1, w2, inarr, wf, w1h, w2h);
  l0gemm_kernel<<<NROW / 16, 256, 0, stream>>>(inarr, wf + W0T, out0);
  rowsum_kernel<<<B_ * 31 * 17, 256, 0, stream>>>(out0, rows);
  colsum_kernel<<<B_ * KK_, 256, 0, stream>>>(rows, m0v);
  tmean0_kernel<<<B_, 256, 0, stream>>>(out0, tm0v);
  chain_kernel<<<B_ * KK_ + B_, 512, 0, stream>>>(out0, m0v, tm0v, w1h, w2h,
                                                  w3, w4, w5, w6, inarr, outf);
}

// Round 8
// 490.413 us; speedup vs baseline: 1.5934x; 1.1325x over previous
//
#include <hip/hip_runtime.h>

typedef _Float16 half_t;
typedef half_t half4 __attribute__((ext_vector_type(4)));
typedef half_t half8 __attribute__((ext_vector_type(8)));
typedef float  f32x4 __attribute__((ext_vector_type(4)));

constexpr int B_  = 8;
constexpr int S_  = 15;
constexpr int K_  = 17;
constexpr int P_  = 31;
constexpr int SS_ = 225;
constexpr int PP_ = 961;
constexpr int KK_ = 289;

constexpr int NROW_C = B_ * PP_;          // 7688
constexpr int NROW_T = B_ * SS_;          // 1800
constexpr int NROW   = NROW_C + NROW_T;   // 9488

// transposed-weight arena offsets (floats): w_iT[cin][cout]
constexpr int W0T = 0;          // [512][256]
constexpr int W1T = 131072;     // [256][128]
constexpr int W2T = 163840;     // [128][64]
constexpr int W3T = 172032;     // [64][32]
constexpr int W4T = 174080;     // [32][16]
constexpr int W5T = 174592;     // [16][8]
constexpr int W6O = 174720;     // [8]
constexpr int WTOT = 174728;
constexpr int NF16 = 128*256 + 64*128 + 32*64;   // w1h | w2h | w3h

// workspace float offsets
constexpr size_t OFF_WF   = 0;
constexpr size_t OFF_IN   = WTOT;
constexpr size_t OFF_OUT0 = OFF_IN   + (size_t)NROW * 256;
constexpr size_t OFF_ROWS = OFF_OUT0 + (size_t)NROW * 512;
constexpr size_t OFF_M0   = OFF_ROWS + (size_t)B_ * 31 * 17 * 256;
constexpr size_t OFF_TM0  = OFF_M0   + (size_t)B_ * KK_ * 256;
constexpr size_t OFF_W1H  = OFF_TM0  + (size_t)B_ * 256;

// chain LDS layout (floats). Region0 @0 (x0 f16 [64][512B swz] | x2 f16 [64][128B swz] | x4 f32 [16][65])
// Region1 @8192 floats (x1 f16 [64][256B swz] | x3 f32 [32][65] | x5 f32 [8][65])
constexpr int ST   = 65;
constexpr int X4F  = 0;
constexpr int X1F  = 8192;
constexpr int X3F  = 8192;
constexpr int X5F  = 8192;
constexpr int SM_OFF  = 12288;
constexpr int RED_OFF = 12528;
constexpr int LDSF = 12544;   // 50176 bytes

// ---------------------------------------------------------------------------
__global__ __launch_bounds__(256) void prep_kernel(
    const float* __restrict__ templ, const float* __restrict__ cand,
    const float* __restrict__ w0, const float* __restrict__ w1,
    const float* __restrict__ w2, const float* __restrict__ w3,
    const float* __restrict__ w4, const float* __restrict__ w5,
    const float* __restrict__ w6,
    float* __restrict__ inarr, float* __restrict__ wf,
    half_t* __restrict__ w1h, half_t* __restrict__ w2h,
    half_t* __restrict__ w3h)
{
  const int NA = NROW_C * 256;
  const int NB = NROW_T * 256;
  const int total = NA + NB + WTOT + NF16;
  for (int idx = blockIdx.x * blockDim.x + threadIdx.x; idx < total;
       idx += gridDim.x * blockDim.x) {
    if (idx < NA) {
      int c = idx & 255; int r = idx >> 8;
      int q = r % P_; int p = (r / P_) % P_; int b = r / PP_;
      inarr[idx] = cand[((b * 256 + c) * P_ + p) * P_ + q];
    } else if (idx < NA + NB) {
      int t = idx - NA;
      int c = t & 255; int r = t >> 8;
      int j = r % S_; int i = (r / S_) % S_; int b = r / SS_;
      inarr[idx] = templ[((b * 256 + c) * S_ + i) * S_ + j];
    } else if (idx < NA + NB + WTOT) {
      int t = idx - NA - NB;
      if (t < W1T) {            // w0T [512][256]
        int o = t & 255; int c = t >> 8;
        wf[t] = w0[o * 512 + c];
      } else if (t < W2T) {
        int u = t - W1T; int o = u & 127; int c = u >> 7;
        wf[t] = w1[o * 256 + c];
      } else if (t < W3T) {
        int u = t - W2T; int o = u & 63; int c = u >> 6;
        wf[t] = w2[o * 128 + c];
      } else if (t < W4T) {
        int u = t - W3T; int o = u & 31; int c = u >> 5;
        wf[t] = w3[o * 64 + c];
      } else if (t < W5T) {
        int u = t - W4T; int o = u & 15; int c = u >> 4;
        wf[t] = w4[o * 32 + c];
      } else if (t < W6O) {
        int u = t - W5T; int o = u & 7; int c = u >> 3;
        wf[t] = w5[o * 16 + c];
      } else {
        wf[t] = w6[t - W6O];
      }
    } else {
      int t = idx - NA - NB - WTOT;
      if (t < 32768)            w1h[t] = (half_t)w1[t];              // [128][256]
      else if (t < 40960)       w2h[t - 32768] = (half_t)w2[t - 32768]; // [64][128]
      else                      w3h[t - 40960] = (half_t)w3[t - 40960]; // [32][64]
    }
  }
}

// ---------------------------------------------------------------------------
__global__ __launch_bounds__(256) void l0gemm_kernel(
    const float* __restrict__ in, const float* __restrict__ w0T,
    float* __restrict__ out0)
{
  __shared__ float X[256 * 17];
  const int tid = threadIdx.x;
  const int row0 = blockIdx.x * 16;
#pragma unroll
  for (int r = 0; r < 16; ++r)
    X[tid * 17 + r] = in[(size_t)(row0 + r) * 256 + tid];
  __syncthreads();
  float accA[16], accB[16];
#pragma unroll
  for (int r = 0; r < 16; ++r) { accA[r] = 0.f; accB[r] = 0.f; }
  for (int c = 0; c < 256; ++c) {
    float wA = w0T[c * 256 + tid];
    float wB = w0T[(256 + c) * 256 + tid];
#pragma unroll
    for (int r = 0; r < 16; ++r) {
      float x = X[c * 17 + r];
      accB[r] = fmaf(wB, x, accB[r]);
      accA[r] = fmaf(wA, x, accA[r]);
    }
  }
#pragma unroll
  for (int r = 0; r < 16; ++r) {
    out0[(size_t)(row0 + r) * 512 + tid]       = accB[r];
    out0[(size_t)(row0 + r) * 512 + 256 + tid] = accA[r];
  }
}

// ---------------------------------------------------------------------------
__global__ __launch_bounds__(256) void rowsum_kernel(
    const float* __restrict__ out0, float* __restrict__ rows)
{
  const int bid = blockIdx.x;
  const int o = threadIdx.x;
  const int v = bid % 17; const int p = (bid / 17) % 31; const int b = bid / (17 * 31);
  float s = 0.f;
  for (int j = 0; j < 15; ++j)
    s += out0[(size_t)(b * PP_ + p * P_ + v + j) * 512 + 256 + o];
  rows[(size_t)bid * 256 + o] = s;
}

__global__ __launch_bounds__(256) void colsum_kernel(
    const float* __restrict__ rows, float* __restrict__ m0v)
{
  const int bid = blockIdx.x;
  const int o = threadIdx.x;
  const int v = bid % 17; const int u = (bid / 17) % 17; const int b = bid / KK_;
  float s = 0.f;
  for (int i = 0; i < 15; ++i)
    s += rows[(size_t)((b * 31 + u + i) * 17 + v) * 256 + o];
  m0v[(size_t)bid * 256 + o] = s * (1.0f / 225.0f);
}

__global__ __launch_bounds__(256) void tmean0_kernel(
    const float* __restrict__ out0, float* __restrict__ tm0v)
{
  const int b = blockIdx.x;
  const int o = threadIdx.x;
  float s = 0.f;
  for (int t = 0; t < SS_; ++t)
    s += out0[(size_t)(NROW_C + b * SS_ + t) * 512 + 256 + o];
  tm0v[b * 256 + o] = s * (1.0f / 225.0f);
}

// ---------------------------------------------------------------------------
template <int CIN, int NPW>
__device__ __forceinline__ void mlp_layer(
    const float* __restrict__ Wt, const float* __restrict__ src,
    float* __restrict__ dst, int lane, int wvs)
{
  constexpr int COUT = 8 * NPW;
  float acc[NPW];
#pragma unroll
  for (int k = 0; k < NPW; ++k) acc[k] = 0.f;
  const float* wbase = Wt + wvs * NPW;
#pragma unroll 4
  for (int c = 0; c < CIN; ++c) {
    float x = src[c * ST + lane];
#pragma unroll
    for (int k = 0; k < NPW; ++k)
      acc[k] = fmaf(wbase[c * COUT + k], x, acc[k]);
  }
#pragma unroll
  for (int k = 0; k < NPW; ++k) {
    float vv = acc[k];
    vv = fmaxf(vv, 0.01f * vv);
    dst[(wvs * NPW + k) * ST + lane] = vv;
  }
}

__global__ __launch_bounds__(512, 3) void chain_kernel(
    const float* __restrict__ out0, const float* __restrict__ m0v,
    const float* __restrict__ tm0v, const float* __restrict__ wf,
    const half_t* __restrict__ w1h, const half_t* __restrict__ w2h,
    const half_t* __restrict__ w3h,
    const float* __restrict__ inarr, float* __restrict__ out)
{
  __shared__ float lds[LDSF];
  char* x0c = (char*)lds;            // f16 x0 [pos][512B] swz, 32 KB
  char* x2c = (char*)lds;            // f16 x2 [pos][128B] swz, 8 KB (alias, x0 dead)
  char* x1c = (char*)(lds + X1F);    // f16 x1 [pos][256B] swz, 16 KB

  const int tid  = threadIdx.x;
  const int lane = tid & 63;
  const int wvs  = __builtin_amdgcn_readfirstlane(tid >> 6);
  const int bid  = (blockIdx.x & 7) * 290 + (blockIdx.x >> 3);   // XCD swizzle (2320 = 8*290)
  const bool is_t = (bid >= B_ * KK_);
  int b, u = 0, v = 0;
  const float* mean_vec;
  if (!is_t) {
    b = bid / KK_;
    int r = bid % KK_;
    u = r / K_; v = r % K_;
    mean_vec = m0v + (size_t)bid * 256;
  } else {
    b = bid - B_ * KK_;
    mean_vec = tm0v + (size_t)b * 256;
  }

  // hoisted MFMA A-fragments (W1: 16 out-ch per wave x 256k; W2: 16 out-ch x 128k)
  half8 af1[8];
  {
    const half_t* base = w1h + (size_t)(16 * wvs + (lane & 15)) * 256 + ((lane >> 4) << 3);
#pragma unroll
    for (int kb = 0; kb < 8; ++kb) af1[kb] = *(const half8*)(base + kb * 32);
  }
  const int g2 = wvs & 3, h2 = wvs >> 2;
  half8 af2[4];
  {
    const half_t* base = w2h + (size_t)(16 * g2 + (lane & 15)) * 128 + ((lane >> 4) << 3);
#pragma unroll
    for (int kb = 0; kb < 4; ++kb) af2[kb] = *(const half8*)(base + kb * 32);
  }
  // L3 wave mapping: row-tile rt3 (16 out-ch), pos-tile ct3 (16 pos)
  const int rt3 = wvs & 1, ct3 = wvs >> 1;
  const half_t* b3ptr = w3h + (size_t)(16 * rt3 + (lane & 15)) * 64 + ((lane >> 4) << 3);
  const f32x4 mv4 = *(const f32x4*)(mean_vec + 4 * lane);

  for (int s0 = 0; s0 < SS_; s0 += 64) {
    const int cnt = min(64, SS_ - s0);
    // ---- stage x0 = f16(leaky(mean + conv1_window)), [pos][256ch] swz
    for (int t = wvs; t < 64; t += 8) {
      int s = min(s0 + t, SS_ - 1);
      size_t row;
      if (!is_t) { int i = s / 15, j = s - i * 15; row = (size_t)(b * PP_ + (u + i) * P_ + (v + j)); }
      else       { row = (size_t)(NROW_C + b * SS_ + s); }
      f32x4 x = *(const f32x4*)(out0 + row * 512 + 4 * lane);
      half4 h;
#pragma unroll
      for (int r = 0; r < 4; ++r) {
        float a = x[r] + mv4[r];
        a = fmaxf(a, 0.01f * a);
        h[r] = (half_t)a;
      }
      const int off = (t * 512 + lane * 8) ^ ((t & 7) << 4);
      *(half4*)(x0c + off) = h;
    }
    __syncthreads();

    // ---- layer 1: 256 -> 128 MFMA (wave owns 16 out-ch, all 64 pos)
    f32x4 acc[4];
#pragma unroll
    for (int nt = 0; nt < 4; ++nt) acc[nt] = (f32x4){0.f, 0.f, 0.f, 0.f};
#pragma unroll
    for (int kb = 0; kb < 8; ++kb) {
      const int kbyte = kb * 64 + ((lane >> 4) << 4);
#pragma unroll
      for (int nt = 0; nt < 4; ++nt) {
        const int pos = nt * 16 + (lane & 15);
        const int off = (pos * 512 + kbyte) ^ ((pos & 7) << 4);
        half8 bfr = *(const half8*)(x0c + off);
        acc[nt] = __builtin_amdgcn_mfma_f32_16x16x32_f16(af1[kb], bfr, acc[nt], 0, 0, 0);
      }
    }
#pragma unroll
    for (int nt = 0; nt < 4; ++nt) {
      const int pos = nt * 16 + (lane & 15);
      half4 h;
#pragma unroll
      for (int r = 0; r < 4; ++r) {
        float a = acc[nt][r];
        a = fmaxf(a, 0.01f * a);
        h[r] = (half_t)a;
      }
      const int ch0 = 16 * wvs + ((lane >> 4) << 2);
      const int off = (pos * 256 + ch0 * 2) ^ ((pos & 7) << 4);
      *(half4*)(x1c + off) = h;
    }
    __syncthreads();

    // ---- layer 2: 128 -> 64 MFMA; epilogue -> x2 f16 [pos][64ch] swz
    f32x4 acc2[2];
#pragma unroll
    for (int nt = 0; nt < 2; ++nt) acc2[nt] = (f32x4){0.f, 0.f, 0.f, 0.f};
#pragma unroll
    for (int kb = 0; kb < 4; ++kb) {
      const int kbyte = kb * 64 + ((lane >> 4) << 4);
#pragma unroll
      for (int nt = 0; nt < 2; ++nt) {
        const int pos = h2 * 32 + nt * 16 + (lane & 15);
        const int off = (pos * 256 + kbyte) ^ ((pos & 7) << 4);
        half8 bfr = *(const half8*)(x1c + off);
        acc2[nt] = __builtin_amdgcn_mfma_f32_16x16x32_f16(af2[kb], bfr, acc2[nt], 0, 0, 0);
      }
    }
#pragma unroll
    for (int nt = 0; nt < 2; ++nt) {
      const int pos = h2 * 32 + nt * 16 + (lane & 15);
      const int ch0 = 16 * g2 + ((lane >> 4) << 2);
      half4 h;
#pragma unroll
      for (int r = 0; r < 4; ++r) {
        float a = acc2[nt][r];
        a = fmaxf(a, 0.01f * a);
        h[r] = (half_t)a;
      }
      const int off = (pos * 128 + ch0 * 2) ^ ((pos & 7) << 4);
      *(half4*)(x2c + off) = h;
    }
    __syncthreads();

    // ---- layer 3: 64 -> 32 MFMA (wave = rt3 x ct3); epilogue -> x3 f32 [ch][65]
    {
      f32x4 acc3 = (f32x4){0.f, 0.f, 0.f, 0.f};
      const int pos = ct3 * 16 + (lane & 15);
#pragma unroll
      for (int kb = 0; kb < 2; ++kb) {
        half8 a3 = *(const half8*)(b3ptr + kb * 32);
        const int kbyte = kb * 64 + ((lane >> 4) << 4);
        const int off = (pos * 128 + kbyte) ^ ((pos & 7) << 4);
        half8 bfr = *(const half8*)(x2c + off);
        acc3 = __builtin_amdgcn_mfma_f32_16x16x32_f16(a3, bfr, acc3, 0, 0, 0);
      }
      const int ch0 = 16 * rt3 + ((lane >> 4) << 2);
#pragma unroll
      for (int r = 0; r < 4; ++r) {
        float a = acc3[r];
        a = fmaxf(a, 0.01f * a);
        lds[X3F + (ch0 + r) * ST + pos] = a;
      }
    }
    __syncthreads();

    // ---- layers 4-5 VALU f32, layer 6 logit
    mlp_layer<32, 2>(wf + W4T, lds + X3F, lds + X4F, lane, wvs); __syncthreads();
    mlp_layer<16, 1>(wf + W5T, lds + X4F, lds + X5F, lane, wvs); __syncthreads();
    if (wvs == 0) {
      float a = 0.f;
#pragma unroll
      for (int o = 0; o < 8; ++o)
        a = fmaf(wf[W6O + o], lds[X5F + o * ST + lane], a);
      if (lane < cnt) lds[SM_OFF + s0 + lane] = a;
    }
    __syncthreads();
  }

  // ---- softmax over 225 logits
  float vv = (tid < SS_) ? lds[SM_OFF + tid] : -1e30f;
  float m = vv;
#pragma unroll
  for (int off = 32; off >= 1; off >>= 1) m = fmaxf(m, __shfl_xor(m, off));
  if (lane == 0) lds[RED_OFF + wvs] = m;
  __syncthreads();
  m = lds[RED_OFF];
#pragma unroll
  for (int w = 1; w < 8; ++w) m = fmaxf(m, lds[RED_OFF + w]);
  float e = (tid < SS_) ? __expf(vv - m) : 0.f;
  float ss = e;
#pragma unroll
  for (int off = 32; off >= 1; off >>= 1) ss += __shfl_xor(ss, off);
  __syncthreads();
  if (lane == 0) lds[RED_OFF + wvs] = ss;
  __syncthreads();
  float Stot = lds[RED_OFF];
#pragma unroll
  for (int w = 1; w < 8; ++w) Stot += lds[RED_OFF + w];
  if (tid < SS_) lds[SM_OFF + tid] = e / Stot;
  __syncthreads();

  // ---- weighted channel sum over raw features
  const int c_st = tid & 255;
  const int h_st = tid >> 8;
  float acc3 = 0.f;
  if (!is_t) {
    for (int s = h_st; s < SS_; s += 2) {
      int i = s / 15, j = s - i * 15;
      size_t row = (size_t)b * PP_ + (u + i) * P_ + (v + j);
      acc3 = fmaf(lds[SM_OFF + s], inarr[row * 256 + c_st], acc3);
    }
  } else {
    for (int s = h_st; s < SS_; s += 2)
      acc3 = fmaf(lds[SM_OFF + s], inarr[(size_t)(NROW_C + b * SS_ + s) * 256 + c_st], acc3);
  }
  __syncthreads();
  lds[tid] = acc3;
  __syncthreads();
  if (tid < 256) {
    float tot = lds[tid] + lds[256 + tid];
    if (!is_t) out[2048 + ((size_t)(b * 256 + tid) * 17 + u) * 17 + v] = tot;
    else       out[b * 256 + tid] = tot;
  }
}

// ---------------------------------------------------------------------------
extern "C" void kernel_launch(void* const* d_in, const int* in_sizes, int n_in,
                              void* d_out, int out_size, void* d_ws, size_t ws_size,
                              hipStream_t stream)
{
  const float* templ = (const float*)d_in[0];
  const float* cand  = (const float*)d_in[1];
  const float* w0 = (const float*)d_in[2];
  const float* w1 = (const float*)d_in[3];
  const float* w2 = (const float*)d_in[4];
  const float* w3 = (const float*)d_in[5];
  const float* w4 = (const float*)d_in[6];
  const float* w5 = (const float*)d_in[7];
  const float* w6 = (const float*)d_in[8];

  float* ws    = (float*)d_ws;
  float* wf    = ws + OFF_WF;
  float* inarr = ws + OFF_IN;
  float* out0  = ws + OFF_OUT0;
  float* rows  = ws + OFF_ROWS;
  float* m0v   = ws + OFF_M0;
  float* tm0v  = ws + OFF_TM0;
  half_t* w1h  = (half_t*)(ws + OFF_W1H);
  half_t* w2h  = w1h + 128 * 256;
  half_t* w3h  = w2h + 64 * 128;
  float* outf  = (float*)d_out;

  prep_kernel<<<2048, 256, 0, stream>>>(templ, cand, w0, w1, w2, w3, w4, w5, w6,
                                        inarr, wf, w1h, w2h, w3h);
  l0gemm_kernel<<<NROW / 16, 256, 0, stream>>>(inarr, wf + W0T, out0);
  rowsum_kernel<<<B_ * 31 * 17, 256, 0, stream>>>(out0, rows);
  colsum_kernel<<<B_ * KK_, 256, 0, stream>>>(rows, m0v);
  tmean0_kernel<<<B_, 256, 0, stream>>>(out0, tm0v);
  chain_kernel<<<B_ * KK_ + B_, 512, 0, stream>>>(out0, m0v, tm0v, wf,
                                                  w1h, w2h, w3h, inarr, outf);
}

// Round 9
// 361.703 us; speedup vs baseline: 2.1605x; 1.3558x over previous
//
#include <hip/hip_runtime.h>

typedef _Float16 half_t;
typedef half_t half4 __attribute__((ext_vector_type(4)));
typedef half_t half8 __attribute__((ext_vector_type(8)));
typedef float  f32x4 __attribute__((ext_vector_type(4)));

constexpr int B_  = 8;
constexpr int S_  = 15;
constexpr int K_  = 17;
constexpr int P_  = 31;
constexpr int SS_ = 225;
constexpr int PP_ = 961;
constexpr int KK_ = 289;

constexpr int NROW_C = B_ * PP_;          // 7688
constexpr int NROW_T = B_ * SS_;          // 1800
constexpr int NROW   = NROW_C + NROW_T;   // 9488

// transposed-weight arena offsets (floats): w_iT[cin][cout]
constexpr int W0T = 0;          // [512][256]
constexpr int W1T = 131072;     // [256][128]
constexpr int W2T = 163840;     // [128][64]
constexpr int W3T = 172032;     // [64][32]
constexpr int W4T = 174080;     // [32][16]
constexpr int W5T = 174592;     // [16][8]
constexpr int W6O = 174720;     // [8]
constexpr int WTOT = 174728;
constexpr int NF16 = 128*256 + 64*128 + 32*64;   // w1h | w2h | w3h

// workspace float offsets
constexpr size_t OFF_WF   = 0;
constexpr size_t OFF_IN   = WTOT;
constexpr size_t OFF_OUT0 = OFF_IN   + (size_t)NROW * 256;
constexpr size_t OFF_ROWS = OFF_OUT0 + (size_t)NROW * 512;
constexpr size_t OFF_M0   = OFF_ROWS + (size_t)B_ * 31 * 17 * 256;
constexpr size_t OFF_TM0  = OFF_M0   + (size_t)B_ * KK_ * 256;
constexpr size_t OFF_W1H  = OFF_TM0  + (size_t)B_ * 256;

// chain LDS layout (floats). Region0 @0 (x0 f16 [64][512B swz] | x2 f16 [64][128B swz] | x4 f32 [16][65])
// Region1 @8192 floats (x1 f16 [64][256B swz] | x3 f32 [32][65] | x5 f32 [8][65])
constexpr int ST   = 65;
constexpr int X4F  = 0;
constexpr int X1F  = 8192;
constexpr int X3F  = 8192;
constexpr int X5F  = 8192;
constexpr int SM_OFF  = 12288;
constexpr int RED_OFF = 12528;
constexpr int LDSF = 12544;   // 50176 bytes

// ---------------------------------------------------------------------------
__global__ __launch_bounds__(256) void prep_kernel(
    const float* __restrict__ templ, const float* __restrict__ cand,
    const float* __restrict__ w0, const float* __restrict__ w1,
    const float* __restrict__ w2, const float* __restrict__ w3,
    const float* __restrict__ w4, const float* __restrict__ w5,
    const float* __restrict__ w6,
    float* __restrict__ inarr, float* __restrict__ wf,
    half_t* __restrict__ w1h, half_t* __restrict__ w2h,
    half_t* __restrict__ w3h)
{
  const int NA = NROW_C * 256;
  const int NB = NROW_T * 256;
  const int total = NA + NB + WTOT + NF16;
  for (int idx = blockIdx.x * blockDim.x + threadIdx.x; idx < total;
       idx += gridDim.x * blockDim.x) {
    if (idx < NA) {
      int c = idx & 255; int r = idx >> 8;
      int q = r % P_; int p = (r / P_) % P_; int b = r / PP_;
      inarr[idx] = cand[((b * 256 + c) * P_ + p) * P_ + q];
    } else if (idx < NA + NB) {
      int t = idx - NA;
      int c = t & 255; int r = t >> 8;
      int j = r % S_; int i = (r / S_) % S_; int b = r / SS_;
      inarr[idx] = templ[((b * 256 + c) * S_ + i) * S_ + j];
    } else if (idx < NA + NB + WTOT) {
      int t = idx - NA - NB;
      if (t < W1T) {            // w0T [512][256]
        int o = t & 255; int c = t >> 8;
        wf[t] = w0[o * 512 + c];
      } else if (t < W2T) {
        int u = t - W1T; int o = u & 127; int c = u >> 7;
        wf[t] = w1[o * 256 + c];
      } else if (t < W3T) {
        int u = t - W2T; int o = u & 63; int c = u >> 6;
        wf[t] = w2[o * 128 + c];
      } else if (t < W4T) {
        int u = t - W3T; int o = u & 31; int c = u >> 5;
        wf[t] = w3[o * 64 + c];
      } else if (t < W5T) {
        int u = t - W4T; int o = u & 15; int c = u >> 4;
        wf[t] = w4[o * 32 + c];
      } else if (t < W6O) {
        int u = t - W5T; int o = u & 7; int c = u >> 3;
        wf[t] = w5[o * 16 + c];
      } else {
        wf[t] = w6[t - W6O];
      }
    } else {
      int t = idx - NA - NB - WTOT;
      if (t < 32768)            w1h[t] = (half_t)w1[t];              // [128][256]
      else if (t < 40960)       w2h[t - 32768] = (half_t)w2[t - 32768]; // [64][128]
      else                      w3h[t - 40960] = (half_t)w3[t - 40960]; // [32][64]
    }
  }
}

// ---------------------------------------------------------------------------
__global__ __launch_bounds__(256) void l0gemm_kernel(
    const float* __restrict__ in, const float* __restrict__ w0T,
    float* __restrict__ out0)
{
  __shared__ float X[256 * 17];
  const int tid = threadIdx.x;
  const int row0 = blockIdx.x * 16;
#pragma unroll
  for (int r = 0; r < 16; ++r)
    X[tid * 17 + r] = in[(size_t)(row0 + r) * 256 + tid];
  __syncthreads();
  float accA[16], accB[16];
#pragma unroll
  for (int r = 0; r < 16; ++r) { accA[r] = 0.f; accB[r] = 0.f; }
  for (int c = 0; c < 256; ++c) {
    float wA = w0T[c * 256 + tid];
    float wB = w0T[(256 + c) * 256 + tid];
#pragma unroll
    for (int r = 0; r < 16; ++r) {
      float x = X[c * 17 + r];
      accB[r] = fmaf(wB, x, accB[r]);
      accA[r] = fmaf(wA, x, accA[r]);
    }
  }
#pragma unroll
  for (int r = 0; r < 16; ++r) {
    out0[(size_t)(row0 + r) * 512 + tid]       = accB[r];
    out0[(size_t)(row0 + r) * 512 + 256 + tid] = accA[r];
  }
}

// ---------------------------------------------------------------------------
__global__ __launch_bounds__(256) void rowsum_kernel(
    const float* __restrict__ out0, float* __restrict__ rows)
{
  const int bid = blockIdx.x;
  const int o = threadIdx.x;
  const int v = bid % 17; const int p = (bid / 17) % 31; const int b = bid / (17 * 31);
  float s = 0.f;
  for (int j = 0; j < 15; ++j)
    s += out0[(size_t)(b * PP_ + p * P_ + v + j) * 512 + 256 + o];
  rows[(size_t)bid * 256 + o] = s;
}

__global__ __launch_bounds__(256) void colsum_kernel(
    const float* __restrict__ rows, float* __restrict__ m0v)
{
  const int bid = blockIdx.x;
  const int o = threadIdx.x;
  const int v = bid % 17; const int u = (bid / 17) % 17; const int b = bid / KK_;
  float s = 0.f;
  for (int i = 0; i < 15; ++i)
    s += rows[(size_t)((b * 31 + u + i) * 17 + v) * 256 + o];
  m0v[(size_t)bid * 256 + o] = s * (1.0f / 225.0f);
}

__global__ __launch_bounds__(256) void tmean0_kernel(
    const float* __restrict__ out0, float* __restrict__ tm0v)
{
  const int b = blockIdx.x;
  const int o = threadIdx.x;
  float s = 0.f;
  for (int t = 0; t < SS_; ++t)
    s += out0[(size_t)(NROW_C + b * SS_ + t) * 512 + 256 + o];
  tm0v[b * 256 + o] = s * (1.0f / 225.0f);
}

// ---------------------------------------------------------------------------
template <int CIN, int NPW>
__device__ __forceinline__ void mlp_layer(
    const float* __restrict__ Wt, const float* __restrict__ src,
    float* __restrict__ dst, int lane, int wvs)
{
  constexpr int COUT = 8 * NPW;
  float acc[NPW];
#pragma unroll
  for (int k = 0; k < NPW; ++k) acc[k] = 0.f;
  const float* wbase = Wt + wvs * NPW;
#pragma unroll 4
  for (int c = 0; c < CIN; ++c) {
    float x = src[c * ST + lane];
#pragma unroll
    for (int k = 0; k < NPW; ++k)
      acc[k] = fmaf(wbase[c * COUT + k], x, acc[k]);
  }
#pragma unroll
  for (int k = 0; k < NPW; ++k) {
    float vv = acc[k];
    vv = fmaxf(vv, 0.01f * vv);
    dst[(wvs * NPW + k) * ST + lane] = vv;
  }
}

__global__ __launch_bounds__(512, 4) void chain_kernel(
    const float* __restrict__ out0, const float* __restrict__ m0v,
    const float* __restrict__ tm0v, const float* __restrict__ wf,
    const half_t* __restrict__ w1h, const half_t* __restrict__ w2h,
    const half_t* __restrict__ w3h,
    const float* __restrict__ inarr, float* __restrict__ out)
{
  __shared__ float lds[LDSF];
  char* x0c = (char*)lds;            // f16 x0 [pos][512B] swz, 32 KB
  char* x2c = (char*)lds;            // f16 x2 [pos][128B] swz, 8 KB (alias, x0 dead)
  char* x1c = (char*)(lds + X1F);    // f16 x1 [pos][256B] swz, 16 KB

  const int tid  = threadIdx.x;
  const int lane = tid & 63;
  const int wvs  = __builtin_amdgcn_readfirstlane(tid >> 6);
  const int bid  = (blockIdx.x & 7) * 290 + (blockIdx.x >> 3);   // XCD swizzle (2320 = 8*290)
  const bool is_t = (bid >= B_ * KK_);
  int b, u = 0, v = 0;
  const float* mean_vec;
  if (!is_t) {
    b = bid / KK_;
    int r = bid % KK_;
    u = r / K_; v = r % K_;
    mean_vec = m0v + (size_t)bid * 256;
  } else {
    b = bid - B_ * KK_;
    mean_vec = tm0v + (size_t)b * 256;
  }

  // hoisted MFMA A-fragments (W1: 16 out-ch per wave x 256k; W2: 16 out-ch x 128k)
  half8 af1[8];
  {
    const half_t* base = w1h + (size_t)(16 * wvs + (lane & 15)) * 256 + ((lane >> 4) << 3);
#pragma unroll
    for (int kb = 0; kb < 8; ++kb) af1[kb] = *(const half8*)(base + kb * 32);
  }
  const int g2 = wvs & 3, h2 = wvs >> 2;
  half8 af2[4];
  {
    const half_t* base = w2h + (size_t)(16 * g2 + (lane & 15)) * 128 + ((lane >> 4) << 3);
#pragma unroll
    for (int kb = 0; kb < 4; ++kb) af2[kb] = *(const half8*)(base + kb * 32);
  }
  // L3 wave mapping: row-tile rt3 (16 out-ch), pos-tile ct3 (16 pos)
  const int rt3 = wvs & 1, ct3 = wvs >> 1;
  const half_t* b3ptr = w3h + (size_t)(16 * rt3 + (lane & 15)) * 64 + ((lane >> 4) << 3);
  const f32x4 mv4 = *(const f32x4*)(mean_vec + 4 * lane);

  for (int s0 = 0; s0 < SS_; s0 += 64) {
    const int cnt = min(64, SS_ - s0);
    // ---- stage x0 = f16(leaky(mean + conv1_window)), [pos][256ch] swz
    for (int t = wvs; t < 64; t += 8) {
      int s = min(s0 + t, SS_ - 1);
      size_t row;
      if (!is_t) { int i = s / 15, j = s - i * 15; row = (size_t)(b * PP_ + (u + i) * P_ + (v + j)); }
      else       { row = (size_t)(NROW_C + b * SS_ + s); }
      f32x4 x = *(const f32x4*)(out0 + row * 512 + 4 * lane);
      half4 h;
#pragma unroll
      for (int r = 0; r < 4; ++r) {
        float a = x[r] + mv4[r];
        a = fmaxf(a, 0.01f * a);
        h[r] = (half_t)a;
      }
      const int off = (t * 512 + lane * 8) ^ ((t & 7) << 4);
      *(half4*)(x0c + off) = h;
    }
    __syncthreads();

    // ---- layer 1: 256 -> 128 MFMA (wave owns 16 out-ch, all 64 pos)
    f32x4 acc[4];
#pragma unroll
    for (int nt = 0; nt < 4; ++nt) acc[nt] = (f32x4){0.f, 0.f, 0.f, 0.f};
#pragma unroll
    for (int kb = 0; kb < 8; ++kb) {
      const int kbyte = kb * 64 + ((lane >> 4) << 4);
#pragma unroll
      for (int nt = 0; nt < 4; ++nt) {
        const int pos = nt * 16 + (lane & 15);
        const int off = (pos * 512 + kbyte) ^ ((pos & 7) << 4);
        half8 bfr = *(const half8*)(x0c + off);
        acc[nt] = __builtin_amdgcn_mfma_f32_16x16x32_f16(af1[kb], bfr, acc[nt], 0, 0, 0);
      }
    }
#pragma unroll
    for (int nt = 0; nt < 4; ++nt) {
      const int pos = nt * 16 + (lane & 15);
      half4 h;
#pragma unroll
      for (int r = 0; r < 4; ++r) {
        float a = acc[nt][r];
        a = fmaxf(a, 0.01f * a);
        h[r] = (half_t)a;
      }
      const int ch0 = 16 * wvs + ((lane >> 4) << 2);
      const int off = (pos * 256 + ch0 * 2) ^ ((pos & 7) << 4);
      *(half4*)(x1c + off) = h;
    }
    __syncthreads();

    // ---- layer 2: 128 -> 64 MFMA; epilogue -> x2 f16 [pos][64ch] swz
    f32x4 acc2[2];
#pragma unroll
    for (int nt = 0; nt < 2; ++nt) acc2[nt] = (f32x4){0.f, 0.f, 0.f, 0.f};
#pragma unroll
    for (int kb = 0; kb < 4; ++kb) {
      const int kbyte = kb * 64 + ((lane >> 4) << 4);
#pragma unroll
      for (int nt = 0; nt < 2; ++nt) {
        const int pos = h2 * 32 + nt * 16 + (lane & 15);
        const int off = (pos * 256 + kbyte) ^ ((pos & 7) << 4);
        half8 bfr = *(const half8*)(x1c + off);
        acc2[nt] = __builtin_amdgcn_mfma_f32_16x16x32_f16(af2[kb], bfr, acc2[nt], 0, 0, 0);
      }
    }
#pragma unroll
    for (int nt = 0; nt < 2; ++nt) {
      const int pos = h2 * 32 + nt * 16 + (lane & 15);
      const int ch0 = 16 * g2 + ((lane >> 4) << 2);
      half4 h;
#pragma unroll
      for (int r = 0; r < 4; ++r) {
        float a = acc2[nt][r];
        a = fmaxf(a, 0.01f * a);
        h[r] = (half_t)a;
      }
      const int off = (pos * 128 + ch0 * 2) ^ ((pos & 7) << 4);
      *(half4*)(x2c + off) = h;
    }
    __syncthreads();

    // ---- layer 3: 64 -> 32 MFMA (wave = rt3 x ct3); epilogue -> x3 f32 [ch][65]
    {
      f32x4 acc3 = (f32x4){0.f, 0.f, 0.f, 0.f};
      const int pos = ct3 * 16 + (lane & 15);
#pragma unroll
      for (int kb = 0; kb < 2; ++kb) {
        half8 a3 = *(const half8*)(b3ptr + kb * 32);
        const int kbyte = kb * 64 + ((lane >> 4) << 4);
        const int off = (pos * 128 + kbyte) ^ ((pos & 7) << 4);
        half8 bfr = *(const half8*)(x2c + off);
        acc3 = __builtin_amdgcn_mfma_f32_16x16x32_f16(a3, bfr, acc3, 0, 0, 0);
      }
      const int ch0 = 16 * rt3 + ((lane >> 4) << 2);
#pragma unroll
      for (int r = 0; r < 4; ++r) {
        float a = acc3[r];
        a = fmaxf(a, 0.01f * a);
        lds[X3F + (ch0 + r) * ST + pos] = a;
      }
    }
    __syncthreads();

    // ---- layers 4-5 VALU f32, layer 6 logit
    mlp_layer<32, 2>(wf + W4T, lds + X3F, lds + X4F, lane, wvs); __syncthreads();
    mlp_layer<16, 1>(wf + W5T, lds + X4F, lds + X5F, lane, wvs); __syncthreads();
    if (wvs == 0) {
      float a = 0.f;
#pragma unroll
      for (int o = 0; o < 8; ++o)
        a = fmaf(wf[W6O + o], lds[X5F + o * ST + lane], a);
      if (lane < cnt) lds[SM_OFF + s0 + lane] = a;
    }
    __syncthreads();
  }

  // ---- softmax over 225 logits
  float vv = (tid < SS_) ? lds[SM_OFF + tid] : -1e30f;
  float m = vv;
#pragma unroll
  for (int off = 32; off >= 1; off >>= 1) m = fmaxf(m, __shfl_xor(m, off));
  if (lane == 0) lds[RED_OFF + wvs] = m;
  __syncthreads();
  m = lds[RED_OFF];
#pragma unroll
  for (int w = 1; w < 8; ++w) m = fmaxf(m, lds[RED_OFF + w]);
  float e = (tid < SS_) ? __expf(vv - m) : 0.f;
  float ss = e;
#pragma unroll
  for (int off = 32; off >= 1; off >>= 1) ss += __shfl_xor(ss, off);
  __syncthreads();
  if (lane == 0) lds[RED_OFF + wvs] = ss;
  __syncthreads();
  float Stot = lds[RED_OFF];
#pragma unroll
  for (int w = 1; w < 8; ++w) Stot += lds[RED_OFF + w];
  if (tid < SS_) lds[SM_OFF + tid] = e / Stot;
  __syncthreads();

  // ---- weighted channel sum over raw features
  const int c_st = tid & 255;
  const int h_st = tid >> 8;
  float acc3 = 0.f;
  if (!is_t) {
    for (int s = h_st; s < SS_; s += 2) {
      int i = s / 15, j = s - i * 15;
      size_t row = (size_t)b * PP_ + (u + i) * P_ + (v + j);
      acc3 = fmaf(lds[SM_OFF + s], inarr[row * 256 + c_st], acc3);
    }
  } else {
    for (int s = h_st; s < SS_; s += 2)
      acc3 = fmaf(lds[SM_OFF + s], inarr[(size_t)(NROW_C + b * SS_ + s) * 256 + c_st], acc3);
  }
  __syncthreads();
  lds[tid] = acc3;
  __syncthreads();
  if (tid < 256) {
    float tot = lds[tid] + lds[256 + tid];
    if (!is_t) out[2048 + ((size_t)(b * 256 + tid) * 17 + u) * 17 + v] = tot;
    else       out[b * 256 + tid] = tot;
  }
}

// ---------------------------------------------------------------------------
extern "C" void kernel_launch(void* const* d_in, const int* in_sizes, int n_in,
                              void* d_out, int out_size, void* d_ws, size_t ws_size,
                              hipStream_t stream)
{
  const float* templ = (const float*)d_in[0];
  const float* cand  = (const float*)d_in[1];
  const float* w0 = (const float*)d_in[2];
  const float* w1 = (const float*)d_in[3];
  const float* w2 = (const float*)d_in[4];
  const float* w3 = (const float*)d_in[5];
  const float* w4 = (const float*)d_in[6];
  const float* w5 = (const float*)d_in[7];
  const float* w6 = (const float*)d_in[8];

  float* ws    = (float*)d_ws;
  float* wf    = ws + OFF_WF;
  float* inarr = ws + OFF_IN;
  float* out0  = ws + OFF_OUT0;
  float* rows  = ws + OFF_ROWS;
  float* m0v   = ws + OFF_M0;
  float* tm0v  = ws + OFF_TM0;
  half_t* w1h  = (half_t*)(ws + OFF_W1H);
  half_t* w2h  = w1h + 128 * 256;
  half_t* w3h  = w2h + 64 * 128;
  float* outf  = (float*)d_out;

  prep_kernel<<<2048, 256, 0, stream>>>(templ, cand, w0, w1, w2, w3, w4, w5, w6,
                                        inarr, wf, w1h, w2h, w3h);
  l0gemm_kernel<<<NROW / 16, 256, 0, stream>>>(inarr, wf + W0T, out0);
  rowsum_kernel<<<B_ * 31 * 17, 256, 0, stream>>>(out0, rows);
  colsum_kernel<<<B_ * KK_, 256, 0, stream>>>(rows, m0v);
  tmean0_kernel<<<B_, 256, 0, stream>>>(out0, tm0v);
  chain_kernel<<<B_ * KK_ + B_, 512, 0, stream>>>(out0, m0v, tm0v, wf,
                                                  w1h, w2h, w3h, inarr, outf);
}